// Round 6
// baseline (201.478 us; speedup 1.0000x reference)
//
#include <hip/hip_runtime.h>

#define N_TOK 32768
#define D 256
#define DFF 1024
#define NE 8
#define TB 64    // tokens per expert_ffn block

typedef __attribute__((ext_vector_type(16))) float f32x16;
typedef __attribute__((ext_vector_type(8)))  short bf16x8;

// fp32 -> bf16 round-to-nearest-even
__device__ __forceinline__ unsigned short f2bf(float f) {
    union { float f; unsigned u; } v; v.f = f;
    unsigned r = v.u + 0x7FFFu + ((v.u >> 16) & 1u);
    return (unsigned short)(r >> 16);
}

// ===========================================================================
// Prepass: w1 [E][D=256 d][DFF=1024 f] fp32 -> frag-major bf16 (GEMM1-A).
// frag = (e*32+fblk)*16 + dblk; element (lane l, j): f = fblk*32 + (l&31),
// d = dblk*16 + (l>>5)*8 + j.  (verified rounds 2-5)
// ===========================================================================
__global__ __launch_bounds__(256) void w1f_prep(
    const float* __restrict__ w1, short* __restrict__ w1f) {
    const int gid  = blockIdx.x * 256 + threadIdx.x;
    const int lane = gid & 63;
    const int frag = gid >> 6;
    const int dblk = frag & 15;
    const int fblk = (frag >> 4) & 31;
    const int e    = frag >> 9;
    const int l31 = lane & 31, g = lane >> 5;

    const float* src = w1 + ((size_t)e * 256 + dblk * 16 + g * 8) * 1024
                          + fblk * 32 + l31;
    unsigned u[4];
#pragma unroll
    for (int jp = 0; jp < 4; ++jp) {
        float a = src[(size_t)(jp * 2)     * 1024];
        float b = src[(size_t)(jp * 2 + 1) * 1024];
        u[jp] = (unsigned)f2bf(a) | ((unsigned)f2bf(b) << 16);
    }
    *(uint4*)(w1f + (size_t)gid * 8) = make_uint4(u[0], u[1], u[2], u[3]);
}

// ===========================================================================
// Prepass: w2 [E][DFF f][D col] fp32 -> frag-major bf16 (GEMM2-B).
// frag = (e*8+cblk)*64 + fblk; element: col = cblk*32 + (l&31),
// f = fblk*16 + (l>>5)*8 + j.  (verified rounds 2-5)
// ===========================================================================
__global__ __launch_bounds__(256) void w2f_prep(
    const float* __restrict__ w2, short* __restrict__ w2f) {
    const int gid  = blockIdx.x * 256 + threadIdx.x;
    const int lane = gid & 63;
    const int frag = gid >> 6;
    const int fblk = frag & 63;
    const int cblk = (frag >> 6) & 7;
    const int e    = frag >> 9;
    const int l31 = lane & 31, g = lane >> 5;

    const float* src = w2 + ((size_t)e * 1024 + fblk * 16 + g * 8) * 256
                          + cblk * 32 + l31;
    unsigned u[4];
#pragma unroll
    for (int jp = 0; jp < 4; ++jp) {
        float a = src[(size_t)(jp * 2)     * 256];
        float b = src[(size_t)(jp * 2 + 1) * 256];
        u[jp] = (unsigned)f2bf(a) | ((unsigned)f2bf(b) << 16);
    }
    *(uint4*)(w2f + (size_t)gid * 8) = make_uint4(u[0], u[1], u[2], u[3]);
}

// ===========================================================================
// Gate phase A: per-token fp64 logits + top-2 + softmax; per-block histogram.
// ===========================================================================
__global__ __launch_bounds__(128) void gate_compute(
    const float* __restrict__ x, const float* __restrict__ gw,
    const float* __restrict__ gb,
    unsigned* __restrict__ epair, float* __restrict__ probs,
    int* __restrict__ hists) {
    __shared__ float gws[2048];   // [d][e]
    __shared__ int   hist[NE];
    const int tid = threadIdx.x;
#pragma unroll
    for (int i = 0; i < 4; ++i)
        *(float4*)&gws[i * 512 + tid * 4] = *(const float4*)&gw[i * 512 + tid * 4];
    if (tid < NE) hist[tid] = 0;
    __syncthreads();

    const int t = blockIdx.x * 128 + tid;
    const float* xr = x + (size_t)t * D;

    double acc[NE];
#pragma unroll
    for (int e = 0; e < NE; ++e) acc[e] = 0.0;

    for (int d0 = 0; d0 < 256; d0 += 4) {
        float4 xv = *(const float4*)(xr + d0);
        float xa[4] = {xv.x, xv.y, xv.z, xv.w};
#pragma unroll
        for (int j = 0; j < 4; ++j) {
            float4 ga = *(const float4*)&gws[(d0 + j) * 8];
            float4 gbb = *(const float4*)&gws[(d0 + j) * 8 + 4];
            double xd = (double)xa[j];
            acc[0] += xd * (double)ga.x;  acc[1] += xd * (double)ga.y;
            acc[2] += xd * (double)ga.z;  acc[3] += xd * (double)ga.w;
            acc[4] += xd * (double)gbb.x; acc[5] += xd * (double)gbb.y;
            acc[6] += xd * (double)gbb.z; acc[7] += xd * (double)gbb.w;
        }
    }

    double l[NE];
#pragma unroll
    for (int e = 0; e < NE; ++e) l[e] = acc[e] + (double)gb[e];
    int e1 = 0;
#pragma unroll
    for (int e = 1; e < NE; ++e) if (l[e] > l[e1]) e1 = e;
    int e2 = (e1 == 0) ? 1 : 0;
#pragma unroll
    for (int e = 0; e < NE; ++e) if (e != e1 && l[e] > l[e2]) e2 = e;

    double s = 0.0;
#pragma unroll
    for (int e = 0; e < NE; ++e) s += exp(l[e] - l[e1]);

    atomicAdd(&hist[e1], 1);
    atomicAdd(&hist[e2], 1);
    epair[t] = (unsigned)e1 | ((unsigned)e2 << 8);
    probs[2 * t]     = (float)(1.0 / s);
    probs[2 * t + 1] = (float)(exp(l[e2] - l[e1]) / s);
    __syncthreads();
    if (tid < NE) hists[blockIdx.x * NE + tid] = hist[tid];
}

// ===========================================================================
// Gate phase B: exclusive prefix scan of per-block histograms.
// ===========================================================================
__global__ __launch_bounds__(256) void gate_scan(
    const int* __restrict__ hists, int* __restrict__ bases, int* __restrict__ cnt) {
    __shared__ int s[256];
    const int tid = threadIdx.x;
    for (int e = 0; e < NE; ++e) {
        int v = hists[tid * NE + e];
        s[tid] = v;
        __syncthreads();
        for (int off = 1; off < 256; off <<= 1) {
            int t = (tid >= off) ? s[tid - off] : 0;
            __syncthreads();
            s[tid] += t;
            __syncthreads();
        }
        bases[tid * NE + e] = s[tid] - v;
        if (tid == 255) cnt[e] = s[255];
        __syncthreads();
    }
}

// ===========================================================================
// Gate phase C: scatter tokens into per-expert bins at reserved ranges.
// ===========================================================================
__global__ __launch_bounds__(128) void gate_scatter(
    const unsigned* __restrict__ epair, const float* __restrict__ probs,
    const int* __restrict__ bases,
    int* __restrict__ bidx, float* __restrict__ bp) {
    __shared__ int hist[NE], bs[NE];
    const int tid = threadIdx.x;
    if (tid < NE) { hist[tid] = 0; bs[tid] = bases[blockIdx.x * NE + tid]; }
    __syncthreads();
    const int t = blockIdx.x * 128 + tid;
    const unsigned u = epair[t];
    const int e1 = u & 255, e2 = (u >> 8) & 255;
    const float p1 = probs[2 * t], p2 = probs[2 * t + 1];
    const int pos1 = atomicAdd(&hist[e1], 1);
    const int pos2 = atomicAdd(&hist[e2], 1);
    const int o1 = e1 * N_TOK + bs[e1] + pos1;
    const int o2 = e2 * N_TOK + bs[e2] + pos2;
    bidx[o1] = t;  bp[o1] = p1;
    bidx[o2] = t;  bp[o2] = p2;
}

// ===========================================================================
// Expert FFN v6 = v5 + deep weight prefetch + hs dbuf (1 barrier/fchunk).
// Block = 64 tok x 256 out, 4 waves, 2 blocks/CU. fchunk = 128 f, 8 iters.
// Prefetch schedule (hides ~200cyc L2 latency that capped v5 at 18% util):
//   - w1 low-half (db 0..7) of fchunk fc+1 issued BEFORE fc's barrier
//     (arrives a whole GEMM2 + barrier later);
//   - w1 high-half (db 8..15) batch-issued at GEMM1 start;
//   - w2 fb 0..3 batch-issued before the barrier; fb 4..7 rolling in GEMM2.
//   - hs double-buffered -> post-GEMM1 WAR barrier deleted.
// All frag arrays statically indexed (no scratch). Layouts unchanged from
// verified rounds 2-5. blockIdx&7 = expert -> per-XCD L2 weight affinity.
// ===========================================================================
__global__ __launch_bounds__(256, 2) void expert_ffn(
    const float* __restrict__ x,
    const short* __restrict__ w1f,
    const short* __restrict__ w2f,
    const float* __restrict__ b1, const float* __restrict__ b2,
    const int* __restrict__ cnt, const int* __restrict__ bidx,
    const float* __restrict__ bp, float* __restrict__ out) {
    const int e    = blockIdx.x & 7;
    const int tile = blockIdx.x >> 3;
    const int n_e  = cnt[e];
    const int row0 = tile * TB;
    if (row0 >= n_e) return;

    __shared__ short xs[16 * 64 * 16];   // 32KB [dblk][tok][16] frag-major
    __shared__ short hs[2][16 * 512];    // 32KB dbuf [frag(fb*2+tp)][512]
    __shared__ int   tok_s[TB];
    __shared__ float p_s[TB];

    const int tid  = threadIdx.x;
    const int lane = tid & 63, wid = tid >> 6;
    const int l31  = lane & 31, g = lane >> 5;

    if (tid < TB) {
        int r = row0 + tid;
        tok_s[tid] = (r < n_e) ? bidx[e * N_TOK + r] : -1;
        p_s[tid]   = (r < n_e) ? bp[e * N_TOK + r] : 0.f;
    }
    __syncthreads();

    // ---- stage x -> xs (bf16 frag-major): element (tok, d=db*16+g*8+j)
    // at xs[db*1024 + tok*16 + g*8 + j]. Invalid rows zero-filled.
    {
        const int tok = tid >> 2;
        const int tk  = tok_s[tok];
        const float* xrow = x + (size_t)(tk < 0 ? 0 : tk) * D;
#pragma unroll
        for (int i = 0; i < 4; ++i) {
            const int dblk = (tid & 3) * 4 + i;
            unsigned u[8];
            if (tk >= 0) {
#pragma unroll
                for (int q = 0; q < 4; ++q) {
                    float4 v = *(const float4*)(xrow + dblk * 16 + q * 4);
                    u[q * 2 + 0] = (unsigned)f2bf(v.x) | ((unsigned)f2bf(v.y) << 16);
                    u[q * 2 + 1] = (unsigned)f2bf(v.z) | ((unsigned)f2bf(v.w) << 16);
                }
            } else {
#pragma unroll
                for (int q = 0; q < 8; ++q) u[q] = 0;
            }
            short* dp = &xs[dblk * 1024 + tok * 16];
            *(uint4*)(dp)     = make_uint4(u[0], u[1], u[2], u[3]);
            *(uint4*)(dp + 8) = make_uint4(u[4], u[5], u[6], u[7]);
        }
    }

    f32x16 acc[2][2];   // [tp tok-half][cb col-half]
#pragma unroll
    for (int a = 0; a < 2; ++a)
#pragma unroll
        for (int b = 0; b < 2; ++b)
#pragma unroll
            for (int r = 0; r < 16; ++r) acc[a][b][r] = 0.f;

    const short* w1e = w1f + (size_t)e * (32 * 16 * 512);
    const short* w2e = w2f + (size_t)e * (8 * 64 * 512);
    const float* b1e = b1 + e * DFF;

    // ---- prologue: issue w1 low-half (db 0..7) for fc=0
    bf16x8 w1pre[8];
    {
        const short* w1p0 = w1e + ((size_t)(0 * 4 + wid) * 16) * 512 + lane * 8;
#pragma unroll
        for (int k = 0; k < 8; ++k) w1pre[k] = *(const bf16x8*)(w1p0 + k * 512);
    }

    __syncthreads();   // xs ready

    for (int fc = 0; fc < 8; ++fc) {
        const short* w1c = w1e + ((size_t)(fc * 4 + wid) * 16) * 512 + lane * 8;

        // ---------- GEMM1: wave wid -> f-strip [fc*128+wid*32, +32) x 64 tok
        // batch-issue high half (db 8..15) now; low half already in flight.
        bf16x8 w1hi[8];
#pragma unroll
        for (int k = 0; k < 8; ++k) w1hi[k] = *(const bf16x8*)(w1c + (k + 8) * 512);

        f32x16 h0, h1;
#pragma unroll
        for (int r = 0; r < 16; ++r) { h0[r] = 0.f; h1[r] = 0.f; }

#pragma unroll
        for (int db = 0; db < 8; ++db) {
            bf16x8 x0 = *(const bf16x8*)&xs[db * 1024 + l31 * 16 + g * 8];
            bf16x8 x1 = *(const bf16x8*)&xs[db * 1024 + 512 + l31 * 16 + g * 8];
            h0 = __builtin_amdgcn_mfma_f32_32x32x16_bf16(w1pre[db], x0, h0, 0, 0, 0);
            h1 = __builtin_amdgcn_mfma_f32_32x32x16_bf16(w1pre[db], x1, h1, 0, 0, 0);
        }
#pragma unroll
        for (int db = 0; db < 8; ++db) {
            bf16x8 x0 = *(const bf16x8*)&xs[(8 + db) * 1024 + l31 * 16 + g * 8];
            bf16x8 x1 = *(const bf16x8*)&xs[(8 + db) * 1024 + 512 + l31 * 16 + g * 8];
            h0 = __builtin_amdgcn_mfma_f32_32x32x16_bf16(w1hi[db], x0, h0, 0, 0, 0);
            h1 = __builtin_amdgcn_mfma_f32_32x32x16_bf16(w1hi[db], x1, h1, 0, 0, 0);
        }

        // ---------- pack: bias+relu+bf16 -> hs[fc&1] frag-major
        short* hbuf = &hs[fc & 1][0];
#pragma unroll
        for (int th = 0; th < 2; ++th) {
            const f32x16& hh = th ? h1 : h0;
#pragma unroll
            for (int m = 0; m < 4; ++m) {
                float4 bq = *(const float4*)(b1e + fc * 128 + wid * 32 + 8 * m + 4 * g);
                float v0 = fmaxf(hh[4 * m + 0] + bq.x, 0.f);
                float v1 = fmaxf(hh[4 * m + 1] + bq.y, 0.f);
                float v2 = fmaxf(hh[4 * m + 2] + bq.z, 0.f);
                float v3 = fmaxf(hh[4 * m + 3] + bq.w, 0.f);
                uint2 pk;
                pk.x = (unsigned)f2bf(v0) | ((unsigned)f2bf(v1) << 16);
                pk.y = (unsigned)f2bf(v2) | ((unsigned)f2bf(v3) << 16);
                const int fragid = (2 * wid + (m >> 1)) * 2 + th;
                *(uint2*)&hbuf[fragid * 512 + ((m & 1) * 32 + l31) * 8 + 4 * g] = pk;
            }
        }

        // ---------- batch-issue w2 fb 0..3 (both col-halves) before barrier
        const short* w2p = w2e + ((size_t)(wid * 2) * 64 + fc * 8) * 512 + lane * 8;
        bf16x8 wb[4][2];
#pragma unroll
        for (int fb = 0; fb < 4; ++fb) {
            wb[fb][0] = *(const bf16x8*)(w2p + fb * 512);
            wb[fb][1] = *(const bf16x8*)(w2p + fb * 512 + (size_t)64 * 512);
        }

        // ---------- issue w1 low-half for fc+1 (lands after GEMM2+barrier)
        if (fc < 7) {
            const short* w1n = w1e + ((size_t)((fc + 1) * 4 + wid) * 16) * 512 + lane * 8;
#pragma unroll
            for (int k = 0; k < 8; ++k) w1pre[k] = *(const bf16x8*)(w1n + k * 512);
        }

        __syncthreads();   // hs[fc&1] ready (only barrier per fchunk)

        // ---------- GEMM2: wave wid -> cols [wid*64, +64), k over 128 f
        bf16x8 wr[4][2];
#pragma unroll
        for (int fb = 0; fb < 4; ++fb) {
            bf16x8 ha0 = *(const bf16x8*)&hbuf[(fb * 2 + 0) * 512 + lane * 8];
            bf16x8 ha1 = *(const bf16x8*)&hbuf[(fb * 2 + 1) * 512 + lane * 8];
            wr[fb][0] = *(const bf16x8*)(w2p + (fb + 4) * 512);
            wr[fb][1] = *(const bf16x8*)(w2p + (fb + 4) * 512 + (size_t)64 * 512);
            acc[0][0] = __builtin_amdgcn_mfma_f32_32x32x16_bf16(ha0, wb[fb][0], acc[0][0], 0, 0, 0);
            acc[0][1] = __builtin_amdgcn_mfma_f32_32x32x16_bf16(ha0, wb[fb][1], acc[0][1], 0, 0, 0);
            acc[1][0] = __builtin_amdgcn_mfma_f32_32x32x16_bf16(ha1, wb[fb][0], acc[1][0], 0, 0, 0);
            acc[1][1] = __builtin_amdgcn_mfma_f32_32x32x16_bf16(ha1, wb[fb][1], acc[1][1], 0, 0, 0);
        }
#pragma unroll
        for (int fb = 0; fb < 4; ++fb) {
            bf16x8 ha0 = *(const bf16x8*)&hbuf[((fb + 4) * 2 + 0) * 512 + lane * 8];
            bf16x8 ha1 = *(const bf16x8*)&hbuf[((fb + 4) * 2 + 1) * 512 + lane * 8];
            acc[0][0] = __builtin_amdgcn_mfma_f32_32x32x16_bf16(ha0, wr[fb][0], acc[0][0], 0, 0, 0);
            acc[0][1] = __builtin_amdgcn_mfma_f32_32x32x16_bf16(ha0, wr[fb][1], acc[0][1], 0, 0, 0);
            acc[1][0] = __builtin_amdgcn_mfma_f32_32x32x16_bf16(ha1, wr[fb][0], acc[1][0], 0, 0, 0);
            acc[1][1] = __builtin_amdgcn_mfma_f32_32x32x16_bf16(ha1, wr[fb][1], acc[1][1], 0, 0, 0);
        }
    }

    // ---- epilogue: out[tok] += p*(acc + b2); exactly 2 commutative fp32
    // atomics per output element from a zeroed buffer -> deterministic.
    const float* b2e = b2 + e * D;
#pragma unroll
    for (int tp = 0; tp < 2; ++tp) {
#pragma unroll
        for (int cb = 0; cb < 2; ++cb) {
            const int col = wid * 64 + cb * 32 + l31;
            const float bv = b2e[col];
#pragma unroll
            for (int r = 0; r < 16; ++r) {
                const int tl = tp * 32 + (r & 3) + 8 * (r >> 2) + 4 * g;
                const int tk = tok_s[tl];
                if (tk >= 0)
                    atomicAdd(out + (size_t)tk * D + col,
                              (acc[tp][cb][r] + bv) * p_s[tl]);
            }
        }
    }
}

// ---------------------------------------------------------------------------
extern "C" void kernel_launch(void* const* d_in, const int* in_sizes, int n_in,
                              void* d_out, int out_size, void* d_ws, size_t ws_size,
                              hipStream_t stream) {
    const float* x  = (const float*)d_in[0];
    const float* gw = (const float*)d_in[1];
    const float* gb = (const float*)d_in[2];
    const float* w1 = (const float*)d_in[3];
    const float* b1 = (const float*)d_in[4];
    const float* w2 = (const float*)d_in[5];
    const float* b2 = (const float*)d_in[6];
    float* out = (float*)d_out;

    // ws: cnt 256B | bidx 1MB | bp 1MB | w1f 4MB | w2f 4MB.
    // Gate temporaries alias w1f (consumed before w1f_prep; stream-ordered).
    char* ws = (char*)d_ws;
    int*   cnt   = (int*)ws;
    int*   bidx  = (int*)(ws + 256);
    float* bp    = (float*)(ws + 256 + (size_t)NE * N_TOK * 4);
    short* w1f   = (short*)(ws + 256 + (size_t)NE * N_TOK * 8);
    short* w2f   = w1f + (size_t)NE * D * DFF;

    unsigned* epair = (unsigned*)w1f;                       // 128KB
    float*    probs = (float*)((char*)w1f + (128 << 10));   // 256KB
    int*      hists = (int*)((char*)w1f + (384 << 10));     // 8KB
    int*      bases = (int*)((char*)w1f + (392 << 10));     // 8KB

    hipMemsetAsync(d_out, 0, (size_t)out_size * sizeof(float), stream);

    gate_compute<<<N_TOK / 128, 128, 0, stream>>>(x, gw, gb, epair, probs, hists);
    gate_scan<<<1, 256, 0, stream>>>(hists, bases, cnt);
    gate_scatter<<<N_TOK / 128, 128, 0, stream>>>(epair, probs, bases, bidx, bp);
    w1f_prep<<<1024, 256, 0, stream>>>(w1, w1f);
    w2f_prep<<<1024, 256, 0, stream>>>(w2, w2f);
    expert_ffn<<<NE * (N_TOK / TB), 256, 0, stream>>>(x, w1f, w2f, b1, b2,
                                                      cnt, bidx, bp, out);
}

// Round 7
// 189.848 us; speedup vs baseline: 1.0613x; 1.0613x over previous
//
#include <hip/hip_runtime.h>

#define N_TOK 32768
#define D 256
#define DFF 1024
#define NE 8
#define TB 64    // tokens per expert_ffn block

typedef __attribute__((ext_vector_type(16))) float f32x16;
typedef __attribute__((ext_vector_type(8)))  short bf16x8;

// fp32 -> bf16 round-to-nearest-even
__device__ __forceinline__ unsigned short f2bf(float f) {
    union { float f; unsigned u; } v; v.f = f;
    unsigned r = v.u + 0x7FFFu + ((v.u >> 16) & 1u);
    return (unsigned short)(r >> 16);
}

// ===========================================================================
// Prepass: w1 [E][D=256 d][DFF=1024 f] fp32 -> frag-major bf16 (GEMM1-A).
// frag = (e*32+fblk)*16 + dblk; element (lane l, j): f = fblk*32 + (l&31),
// d = dblk*16 + (l>>5)*8 + j.  (verified rounds 2-6)
// ===========================================================================
__global__ __launch_bounds__(256) void w1f_prep(
    const float* __restrict__ w1, short* __restrict__ w1f) {
    const int gid  = blockIdx.x * 256 + threadIdx.x;
    const int lane = gid & 63;
    const int frag = gid >> 6;
    const int dblk = frag & 15;
    const int fblk = (frag >> 4) & 31;
    const int e    = frag >> 9;
    const int l31 = lane & 31, g = lane >> 5;

    const float* src = w1 + ((size_t)e * 256 + dblk * 16 + g * 8) * 1024
                          + fblk * 32 + l31;
    unsigned u[4];
#pragma unroll
    for (int jp = 0; jp < 4; ++jp) {
        float a = src[(size_t)(jp * 2)     * 1024];
        float b = src[(size_t)(jp * 2 + 1) * 1024];
        u[jp] = (unsigned)f2bf(a) | ((unsigned)f2bf(b) << 16);
    }
    *(uint4*)(w1f + (size_t)gid * 8) = make_uint4(u[0], u[1], u[2], u[3]);
}

// ===========================================================================
// Prepass: w2 [E][DFF f][D col] fp32 -> frag-major bf16 (GEMM2-B).
// frag = (e*8+cblk)*64 + fblk; element: col = cblk*32 + (l&31),
// f = fblk*16 + (l>>5)*8 + j.  (verified rounds 2-6)
// ===========================================================================
__global__ __launch_bounds__(256) void w2f_prep(
    const float* __restrict__ w2, short* __restrict__ w2f) {
    const int gid  = blockIdx.x * 256 + threadIdx.x;
    const int lane = gid & 63;
    const int frag = gid >> 6;
    const int fblk = frag & 63;
    const int cblk = (frag >> 6) & 7;
    const int e    = frag >> 9;
    const int l31 = lane & 31, g = lane >> 5;

    const float* src = w2 + ((size_t)e * 1024 + fblk * 16 + g * 8) * 256
                          + cblk * 32 + l31;
    unsigned u[4];
#pragma unroll
    for (int jp = 0; jp < 4; ++jp) {
        float a = src[(size_t)(jp * 2)     * 256];
        float b = src[(size_t)(jp * 2 + 1) * 256];
        u[jp] = (unsigned)f2bf(a) | ((unsigned)f2bf(b) << 16);
    }
    *(uint4*)(w2f + (size_t)gid * 8) = make_uint4(u[0], u[1], u[2], u[3]);
}

// ===========================================================================
// Gate phase A: per-token fp64 logits + top-2 + softmax; per-block histogram.
// ===========================================================================
__global__ __launch_bounds__(128) void gate_compute(
    const float* __restrict__ x, const float* __restrict__ gw,
    const float* __restrict__ gb,
    unsigned* __restrict__ epair, float* __restrict__ probs,
    int* __restrict__ hists) {
    __shared__ float gws[2048];   // [d][e]
    __shared__ int   hist[NE];
    const int tid = threadIdx.x;
#pragma unroll
    for (int i = 0; i < 4; ++i)
        *(float4*)&gws[i * 512 + tid * 4] = *(const float4*)&gw[i * 512 + tid * 4];
    if (tid < NE) hist[tid] = 0;
    __syncthreads();

    const int t = blockIdx.x * 128 + tid;
    const float* xr = x + (size_t)t * D;

    double acc[NE];
#pragma unroll
    for (int e = 0; e < NE; ++e) acc[e] = 0.0;

    for (int d0 = 0; d0 < 256; d0 += 4) {
        float4 xv = *(const float4*)(xr + d0);
        float xa[4] = {xv.x, xv.y, xv.z, xv.w};
#pragma unroll
        for (int j = 0; j < 4; ++j) {
            float4 ga = *(const float4*)&gws[(d0 + j) * 8];
            float4 gbb = *(const float4*)&gws[(d0 + j) * 8 + 4];
            double xd = (double)xa[j];
            acc[0] += xd * (double)ga.x;  acc[1] += xd * (double)ga.y;
            acc[2] += xd * (double)ga.z;  acc[3] += xd * (double)ga.w;
            acc[4] += xd * (double)gbb.x; acc[5] += xd * (double)gbb.y;
            acc[6] += xd * (double)gbb.z; acc[7] += xd * (double)gbb.w;
        }
    }

    double l[NE];
#pragma unroll
    for (int e = 0; e < NE; ++e) l[e] = acc[e] + (double)gb[e];
    int e1 = 0;
#pragma unroll
    for (int e = 1; e < NE; ++e) if (l[e] > l[e1]) e1 = e;
    int e2 = (e1 == 0) ? 1 : 0;
#pragma unroll
    for (int e = 0; e < NE; ++e) if (e != e1 && l[e] > l[e2]) e2 = e;

    double s = 0.0;
#pragma unroll
    for (int e = 0; e < NE; ++e) s += exp(l[e] - l[e1]);

    atomicAdd(&hist[e1], 1);
    atomicAdd(&hist[e2], 1);
    epair[t] = (unsigned)e1 | ((unsigned)e2 << 8);
    probs[2 * t]     = (float)(1.0 / s);
    probs[2 * t + 1] = (float)(exp(l[e2] - l[e1]) / s);
    __syncthreads();
    if (tid < NE) hists[blockIdx.x * NE + tid] = hist[tid];
}

// ===========================================================================
// Gate phase B: exclusive prefix scan of per-block histograms.
// ===========================================================================
__global__ __launch_bounds__(256) void gate_scan(
    const int* __restrict__ hists, int* __restrict__ bases, int* __restrict__ cnt) {
    __shared__ int s[256];
    const int tid = threadIdx.x;
    for (int e = 0; e < NE; ++e) {
        int v = hists[tid * NE + e];
        s[tid] = v;
        __syncthreads();
        for (int off = 1; off < 256; off <<= 1) {
            int t = (tid >= off) ? s[tid - off] : 0;
            __syncthreads();
            s[tid] += t;
            __syncthreads();
        }
        bases[tid * NE + e] = s[tid] - v;
        if (tid == 255) cnt[e] = s[255];
        __syncthreads();
    }
}

// ===========================================================================
// Gate phase C: scatter tokens into per-expert bins; record each token's two
// bin slots in opos[t] for the combine pass.
// ===========================================================================
__global__ __launch_bounds__(128) void gate_scatter(
    const unsigned* __restrict__ epair, const float* __restrict__ probs,
    const int* __restrict__ bases,
    int* __restrict__ bidx, float* __restrict__ bp, int2* __restrict__ opos) {
    __shared__ int hist[NE], bs[NE];
    const int tid = threadIdx.x;
    if (tid < NE) { hist[tid] = 0; bs[tid] = bases[blockIdx.x * NE + tid]; }
    __syncthreads();
    const int t = blockIdx.x * 128 + tid;
    const unsigned u = epair[t];
    const int e1 = u & 255, e2 = (u >> 8) & 255;
    const float p1 = probs[2 * t], p2 = probs[2 * t + 1];
    const int pos1 = atomicAdd(&hist[e1], 1);
    const int pos2 = atomicAdd(&hist[e2], 1);
    const int o1 = e1 * N_TOK + bs[e1] + pos1;
    const int o2 = e2 * N_TOK + bs[e2] + pos2;
    bidx[o1] = t;  bp[o1] = p1;
    bidx[o2] = t;  bp[o2] = p2;
    opos[t] = make_int2(o1, o2);
}

// ===========================================================================
// Expert FFN v7 = v6 GEMM (deep weight prefetch, hs dbuf, 1 barrier/fchunk)
// with the ATOMIC-FREE staged epilogue: partials stored bin-contiguously to
// yp[e*N_TOK+pos][256] as plain coalesced fp32 stores (atomics were the
// shared ~100us floor across v3/v5/v6 — 16.7M scattered device-scope RMWs).
// staged=false falls back to the old atomicAdd path (small ws).
// ===========================================================================
__global__ __launch_bounds__(256, 2) void expert_ffn(
    const float* __restrict__ x,
    const short* __restrict__ w1f,
    const short* __restrict__ w2f,
    const float* __restrict__ b1, const float* __restrict__ b2,
    const int* __restrict__ cnt, const int* __restrict__ bidx,
    const float* __restrict__ bp, float* __restrict__ out,
    float* __restrict__ yp, int staged) {
    const int e    = blockIdx.x & 7;
    const int tile = blockIdx.x >> 3;
    const int n_e  = cnt[e];
    const int row0 = tile * TB;
    if (row0 >= n_e) return;

    __shared__ short xs[16 * 64 * 16];   // 32KB [dblk][tok][16] frag-major
    __shared__ short hs[2][16 * 512];    // 32KB dbuf [frag(fb*2+tp)][512]
    __shared__ int   tok_s[TB];
    __shared__ float p_s[TB];

    const int tid  = threadIdx.x;
    const int lane = tid & 63, wid = tid >> 6;
    const int l31  = lane & 31, g = lane >> 5;

    if (tid < TB) {
        int r = row0 + tid;
        tok_s[tid] = (r < n_e) ? bidx[e * N_TOK + r] : -1;
        p_s[tid]   = (r < n_e) ? bp[e * N_TOK + r] : 0.f;
    }
    __syncthreads();

    // ---- stage x -> xs (bf16 frag-major): element (tok, d=db*16+g*8+j)
    // at xs[db*1024 + tok*16 + g*8 + j]. Invalid rows zero-filled.
    {
        const int tok = tid >> 2;
        const int tk  = tok_s[tok];
        const float* xrow = x + (size_t)(tk < 0 ? 0 : tk) * D;
#pragma unroll
        for (int i = 0; i < 4; ++i) {
            const int dblk = (tid & 3) * 4 + i;
            unsigned u[8];
            if (tk >= 0) {
#pragma unroll
                for (int q = 0; q < 4; ++q) {
                    float4 v = *(const float4*)(xrow + dblk * 16 + q * 4);
                    u[q * 2 + 0] = (unsigned)f2bf(v.x) | ((unsigned)f2bf(v.y) << 16);
                    u[q * 2 + 1] = (unsigned)f2bf(v.z) | ((unsigned)f2bf(v.w) << 16);
                }
            } else {
#pragma unroll
                for (int q = 0; q < 8; ++q) u[q] = 0;
            }
            short* dp = &xs[dblk * 1024 + tok * 16];
            *(uint4*)(dp)     = make_uint4(u[0], u[1], u[2], u[3]);
            *(uint4*)(dp + 8) = make_uint4(u[4], u[5], u[6], u[7]);
        }
    }

    f32x16 acc[2][2];   // [tp tok-half][cb col-half]
#pragma unroll
    for (int a = 0; a < 2; ++a)
#pragma unroll
        for (int b = 0; b < 2; ++b)
#pragma unroll
            for (int r = 0; r < 16; ++r) acc[a][b][r] = 0.f;

    const short* w1e = w1f + (size_t)e * (32 * 16 * 512);
    const short* w2e = w2f + (size_t)e * (8 * 64 * 512);
    const float* b1e = b1 + e * DFF;

    // ---- prologue: issue w1 low-half (db 0..7) for fc=0
    bf16x8 w1pre[8];
    {
        const short* w1p0 = w1e + ((size_t)(0 * 4 + wid) * 16) * 512 + lane * 8;
#pragma unroll
        for (int k = 0; k < 8; ++k) w1pre[k] = *(const bf16x8*)(w1p0 + k * 512);
    }

    __syncthreads();   // xs ready

    for (int fc = 0; fc < 8; ++fc) {
        const short* w1c = w1e + ((size_t)(fc * 4 + wid) * 16) * 512 + lane * 8;

        // ---------- GEMM1: wave wid -> f-strip [fc*128+wid*32, +32) x 64 tok
        bf16x8 w1hi[8];
#pragma unroll
        for (int k = 0; k < 8; ++k) w1hi[k] = *(const bf16x8*)(w1c + (k + 8) * 512);

        f32x16 h0, h1;
#pragma unroll
        for (int r = 0; r < 16; ++r) { h0[r] = 0.f; h1[r] = 0.f; }

#pragma unroll
        for (int db = 0; db < 8; ++db) {
            bf16x8 x0 = *(const bf16x8*)&xs[db * 1024 + l31 * 16 + g * 8];
            bf16x8 x1 = *(const bf16x8*)&xs[db * 1024 + 512 + l31 * 16 + g * 8];
            h0 = __builtin_amdgcn_mfma_f32_32x32x16_bf16(w1pre[db], x0, h0, 0, 0, 0);
            h1 = __builtin_amdgcn_mfma_f32_32x32x16_bf16(w1pre[db], x1, h1, 0, 0, 0);
        }
#pragma unroll
        for (int db = 0; db < 8; ++db) {
            bf16x8 x0 = *(const bf16x8*)&xs[(8 + db) * 1024 + l31 * 16 + g * 8];
            bf16x8 x1 = *(const bf16x8*)&xs[(8 + db) * 1024 + 512 + l31 * 16 + g * 8];
            h0 = __builtin_amdgcn_mfma_f32_32x32x16_bf16(w1hi[db], x0, h0, 0, 0, 0);
            h1 = __builtin_amdgcn_mfma_f32_32x32x16_bf16(w1hi[db], x1, h1, 0, 0, 0);
        }

        // ---------- pack: bias+relu+bf16 -> hs[fc&1] frag-major
        short* hbuf = &hs[fc & 1][0];
#pragma unroll
        for (int th = 0; th < 2; ++th) {
            const f32x16& hh = th ? h1 : h0;
#pragma unroll
            for (int m = 0; m < 4; ++m) {
                float4 bq = *(const float4*)(b1e + fc * 128 + wid * 32 + 8 * m + 4 * g);
                float v0 = fmaxf(hh[4 * m + 0] + bq.x, 0.f);
                float v1 = fmaxf(hh[4 * m + 1] + bq.y, 0.f);
                float v2 = fmaxf(hh[4 * m + 2] + bq.z, 0.f);
                float v3 = fmaxf(hh[4 * m + 3] + bq.w, 0.f);
                uint2 pk;
                pk.x = (unsigned)f2bf(v0) | ((unsigned)f2bf(v1) << 16);
                pk.y = (unsigned)f2bf(v2) | ((unsigned)f2bf(v3) << 16);
                const int fragid = (2 * wid + (m >> 1)) * 2 + th;
                *(uint2*)&hbuf[fragid * 512 + ((m & 1) * 32 + l31) * 8 + 4 * g] = pk;
            }
        }

        // ---------- batch-issue w2 fb 0..3 (both col-halves) before barrier
        const short* w2p = w2e + ((size_t)(wid * 2) * 64 + fc * 8) * 512 + lane * 8;
        bf16x8 wb[4][2];
#pragma unroll
        for (int fb = 0; fb < 4; ++fb) {
            wb[fb][0] = *(const bf16x8*)(w2p + fb * 512);
            wb[fb][1] = *(const bf16x8*)(w2p + fb * 512 + (size_t)64 * 512);
        }

        // ---------- issue w1 low-half for fc+1 (lands after GEMM2+barrier)
        if (fc < 7) {
            const short* w1n = w1e + ((size_t)((fc + 1) * 4 + wid) * 16) * 512 + lane * 8;
#pragma unroll
            for (int k = 0; k < 8; ++k) w1pre[k] = *(const bf16x8*)(w1n + k * 512);
        }

        __syncthreads();   // hs[fc&1] ready (only barrier per fchunk)

        // ---------- GEMM2: wave wid -> cols [wid*64, +64), k over 128 f
        bf16x8 wr[4][2];
#pragma unroll
        for (int fb = 0; fb < 4; ++fb) {
            bf16x8 ha0 = *(const bf16x8*)&hbuf[(fb * 2 + 0) * 512 + lane * 8];
            bf16x8 ha1 = *(const bf16x8*)&hbuf[(fb * 2 + 1) * 512 + lane * 8];
            wr[fb][0] = *(const bf16x8*)(w2p + (fb + 4) * 512);
            wr[fb][1] = *(const bf16x8*)(w2p + (fb + 4) * 512 + (size_t)64 * 512);
            acc[0][0] = __builtin_amdgcn_mfma_f32_32x32x16_bf16(ha0, wb[fb][0], acc[0][0], 0, 0, 0);
            acc[0][1] = __builtin_amdgcn_mfma_f32_32x32x16_bf16(ha0, wb[fb][1], acc[0][1], 0, 0, 0);
            acc[1][0] = __builtin_amdgcn_mfma_f32_32x32x16_bf16(ha1, wb[fb][0], acc[1][0], 0, 0, 0);
            acc[1][1] = __builtin_amdgcn_mfma_f32_32x32x16_bf16(ha1, wb[fb][1], acc[1][1], 0, 0, 0);
        }
#pragma unroll
        for (int fb = 0; fb < 4; ++fb) {
            bf16x8 ha0 = *(const bf16x8*)&hbuf[((fb + 4) * 2 + 0) * 512 + lane * 8];
            bf16x8 ha1 = *(const bf16x8*)&hbuf[((fb + 4) * 2 + 1) * 512 + lane * 8];
            acc[0][0] = __builtin_amdgcn_mfma_f32_32x32x16_bf16(ha0, wr[fb][0], acc[0][0], 0, 0, 0);
            acc[0][1] = __builtin_amdgcn_mfma_f32_32x32x16_bf16(ha0, wr[fb][1], acc[0][1], 0, 0, 0);
            acc[1][0] = __builtin_amdgcn_mfma_f32_32x32x16_bf16(ha1, wr[fb][0], acc[1][0], 0, 0, 0);
            acc[1][1] = __builtin_amdgcn_mfma_f32_32x32x16_bf16(ha1, wr[fb][1], acc[1][1], 0, 0, 0);
        }
    }

    // ---- epilogue ----
    const float* b2e = b2 + e * D;
    if (staged) {
        // bin-contiguous coalesced stores; slot (e, row0+tl) written by
        // exactly this block; combine() sums the two slots per token.
        float* ype = yp + ((size_t)e * N_TOK + row0) * 256;
#pragma unroll
        for (int tp = 0; tp < 2; ++tp) {
#pragma unroll
            for (int cb = 0; cb < 2; ++cb) {
                const int col = wid * 64 + cb * 32 + l31;
                const float bv = b2e[col];
#pragma unroll
                for (int r = 0; r < 16; ++r) {
                    const int tl = tp * 32 + (r & 3) + 8 * (r >> 2) + 4 * g;
                    if (tok_s[tl] >= 0)
                        ype[(size_t)tl * 256 + col] = (acc[tp][cb][r] + bv) * p_s[tl];
                }
            }
        }
    } else {
        // fallback: 2 commutative fp32 atomics per out element (zeroed buffer)
#pragma unroll
        for (int tp = 0; tp < 2; ++tp) {
#pragma unroll
            for (int cb = 0; cb < 2; ++cb) {
                const int col = wid * 64 + cb * 32 + l31;
                const float bv = b2e[col];
#pragma unroll
                for (int r = 0; r < 16; ++r) {
                    const int tl = tp * 32 + (r & 3) + 8 * (r >> 2) + 4 * g;
                    const int tk = tok_s[tl];
                    if (tk >= 0)
                        atomicAdd(out + (size_t)tk * D + col,
                                  (acc[tp][cb][r] + bv) * p_s[tl]);
                }
            }
        }
    }
}

// ===========================================================================
// Combine: out[t] = yp[o1] + yp[o2]. One wave per token row (64 lanes x
// float4 = 1KB row); opos read is wave-uniform (scalar broadcast).
// ===========================================================================
__global__ __launch_bounds__(256) void combine(
    const float* __restrict__ yp, const int2* __restrict__ opos,
    float* __restrict__ out) {
    const int gid   = blockIdx.x * 256 + threadIdx.x;  // float4 index
    const int t     = gid >> 6;
    const int lane4 = gid & 63;
    const int2 o = opos[t];
    const float4 a = ((const float4*)yp)[(size_t)o.x * 64 + lane4];
    const float4 b = ((const float4*)yp)[(size_t)o.y * 64 + lane4];
    float4 r;
    r.x = a.x + b.x; r.y = a.y + b.y; r.z = a.z + b.z; r.w = a.w + b.w;
    ((float4*)out)[gid] = r;
}

// ---------------------------------------------------------------------------
extern "C" void kernel_launch(void* const* d_in, const int* in_sizes, int n_in,
                              void* d_out, int out_size, void* d_ws, size_t ws_size,
                              hipStream_t stream) {
    const float* x  = (const float*)d_in[0];
    const float* gw = (const float*)d_in[1];
    const float* gb = (const float*)d_in[2];
    const float* w1 = (const float*)d_in[3];
    const float* b1 = (const float*)d_in[4];
    const float* w2 = (const float*)d_in[5];
    const float* b2 = (const float*)d_in[6];
    float* out = (float*)d_out;

    // ws: cnt 256B | bidx 1MB | bp 1MB | opos 512KB | w1f 4MB | w2f 4MB
    //   | yp 64MB (staged partials).  Gate temporaries alias w1f (consumed
    //   before w1f_prep; stream-ordered).
    char* ws = (char*)d_ws;
    size_t off = 0;
    int*   cnt   = (int*)(ws + off);  off += 256;
    int*   bidx  = (int*)(ws + off);  off += (size_t)NE * N_TOK * 4;
    float* bp    = (float*)(ws + off); off += (size_t)NE * N_TOK * 4;
    int2*  opos  = (int2*)(ws + off); off += (size_t)N_TOK * 8;
    short* w1f   = (short*)(ws + off); off += (size_t)NE * D * DFF * 2;
    short* w2f   = (short*)(ws + off); off += (size_t)NE * D * DFF * 2;
    float* yp    = (float*)(ws + off); off += (size_t)2 * N_TOK * D * 4;
    const int staged = (ws_size >= off) ? 1 : 0;

    unsigned* epair = (unsigned*)w1f;                       // 128KB
    float*    probs = (float*)((char*)w1f + (128 << 10));   // 256KB
    int*      hists = (int*)((char*)w1f + (384 << 10));     // 8KB
    int*      bases = (int*)((char*)w1f + (392 << 10));     // 8KB

    if (!staged)
        hipMemsetAsync(d_out, 0, (size_t)out_size * sizeof(float), stream);

    gate_compute<<<N_TOK / 128, 128, 0, stream>>>(x, gw, gb, epair, probs, hists);
    gate_scan<<<1, 256, 0, stream>>>(hists, bases, cnt);
    gate_scatter<<<N_TOK / 128, 128, 0, stream>>>(epair, probs, bases, bidx, bp, opos);
    w1f_prep<<<1024, 256, 0, stream>>>(w1, w1f);
    w2f_prep<<<1024, 256, 0, stream>>>(w2, w2f);
    expert_ffn<<<NE * (N_TOK / TB), 256, 0, stream>>>(x, w1f, w2f, b1, b2,
                                                      cnt, bidx, bp, out, yp, staged);
    if (staged)
        combine<<<(N_TOK * D / 4) / 256, 256, 0, stream>>>(yp, opos, out);
}

// Round 8
// 179.579 us; speedup vs baseline: 1.1219x; 1.0572x over previous
//
#include <hip/hip_runtime.h>

#define N_TOK 32768
#define D 256
#define DFF 1024
#define NE 8
#define TB 64    // tokens per expert_ffn block

typedef __attribute__((ext_vector_type(16))) float f32x16;
typedef __attribute__((ext_vector_type(8)))  short bf16x8;

// Raw barrier: LDS writes made visible (lgkmcnt(0)) but NO vmcnt drain --
// in-flight global weight loads survive the barrier (the __syncthreads
// vmcnt(0) drain was killing all cross-phase prefetch; m97/T4 analysis).
#define BARRIER() do {                                        \
    asm volatile("s_waitcnt lgkmcnt(0)" ::: "memory");        \
    __builtin_amdgcn_s_barrier();                             \
    __builtin_amdgcn_sched_barrier(0);                        \
} while (0)

// fp32 -> bf16 round-to-nearest-even
__device__ __forceinline__ unsigned short f2bf(float f) {
    union { float f; unsigned u; } v; v.f = f;
    unsigned r = v.u + 0x7FFFu + ((v.u >> 16) & 1u);
    return (unsigned short)(r >> 16);
}

// ===========================================================================
// Prepass: w1 [E][D=256 d][DFF=1024 f] fp32 -> frag-major bf16 (GEMM1-A).
// frag = (e*32+fblk)*16 + dblk; element (lane l, j): f = fblk*32 + (l&31),
// d = dblk*16 + (l>>5)*8 + j.  (verified rounds 2-7)
// ===========================================================================
__global__ __launch_bounds__(256) void w1f_prep(
    const float* __restrict__ w1, short* __restrict__ w1f) {
    const int gid  = blockIdx.x * 256 + threadIdx.x;
    const int lane = gid & 63;
    const int frag = gid >> 6;
    const int dblk = frag & 15;
    const int fblk = (frag >> 4) & 31;
    const int e    = frag >> 9;
    const int l31 = lane & 31, g = lane >> 5;

    const float* src = w1 + ((size_t)e * 256 + dblk * 16 + g * 8) * 1024
                          + fblk * 32 + l31;
    unsigned u[4];
#pragma unroll
    for (int jp = 0; jp < 4; ++jp) {
        float a = src[(size_t)(jp * 2)     * 1024];
        float b = src[(size_t)(jp * 2 + 1) * 1024];
        u[jp] = (unsigned)f2bf(a) | ((unsigned)f2bf(b) << 16);
    }
    *(uint4*)(w1f + (size_t)gid * 8) = make_uint4(u[0], u[1], u[2], u[3]);
}

// ===========================================================================
// Prepass: w2 [E][DFF f][D col] fp32 -> frag-major bf16 (GEMM2-B).
// frag = (e*8+cblk)*64 + fblk; element: col = cblk*32 + (l&31),
// f = fblk*16 + (l>>5)*8 + j.  (verified rounds 2-7)
// ===========================================================================
__global__ __launch_bounds__(256) void w2f_prep(
    const float* __restrict__ w2, short* __restrict__ w2f) {
    const int gid  = blockIdx.x * 256 + threadIdx.x;
    const int lane = gid & 63;
    const int frag = gid >> 6;
    const int fblk = frag & 63;
    const int cblk = (frag >> 6) & 7;
    const int e    = frag >> 9;
    const int l31 = lane & 31, g = lane >> 5;

    const float* src = w2 + ((size_t)e * 1024 + fblk * 16 + g * 8) * 256
                          + cblk * 32 + l31;
    unsigned u[4];
#pragma unroll
    for (int jp = 0; jp < 4; ++jp) {
        float a = src[(size_t)(jp * 2)     * 256];
        float b = src[(size_t)(jp * 2 + 1) * 256];
        u[jp] = (unsigned)f2bf(a) | ((unsigned)f2bf(b) << 16);
    }
    *(uint4*)(w2f + (size_t)gid * 8) = make_uint4(u[0], u[1], u[2], u[3]);
}

// ===========================================================================
// Gate phase A: per-token fp64 logits + top-2 + softmax; per-block histogram.
// ===========================================================================
__global__ __launch_bounds__(128) void gate_compute(
    const float* __restrict__ x, const float* __restrict__ gw,
    const float* __restrict__ gb,
    unsigned* __restrict__ epair, float* __restrict__ probs,
    int* __restrict__ hists) {
    __shared__ float gws[2048];   // [d][e]
    __shared__ int   hist[NE];
    const int tid = threadIdx.x;
#pragma unroll
    for (int i = 0; i < 4; ++i)
        *(float4*)&gws[i * 512 + tid * 4] = *(const float4*)&gw[i * 512 + tid * 4];
    if (tid < NE) hist[tid] = 0;
    __syncthreads();

    const int t = blockIdx.x * 128 + tid;
    const float* xr = x + (size_t)t * D;

    double acc[NE];
#pragma unroll
    for (int e = 0; e < NE; ++e) acc[e] = 0.0;

    for (int d0 = 0; d0 < 256; d0 += 4) {
        float4 xv = *(const float4*)(xr + d0);
        float xa[4] = {xv.x, xv.y, xv.z, xv.w};
#pragma unroll
        for (int j = 0; j < 4; ++j) {
            float4 ga = *(const float4*)&gws[(d0 + j) * 8];
            float4 gbb = *(const float4*)&gws[(d0 + j) * 8 + 4];
            double xd = (double)xa[j];
            acc[0] += xd * (double)ga.x;  acc[1] += xd * (double)ga.y;
            acc[2] += xd * (double)ga.z;  acc[3] += xd * (double)ga.w;
            acc[4] += xd * (double)gbb.x; acc[5] += xd * (double)gbb.y;
            acc[6] += xd * (double)gbb.z; acc[7] += xd * (double)gbb.w;
        }
    }

    double l[NE];
#pragma unroll
    for (int e = 0; e < NE; ++e) l[e] = acc[e] + (double)gb[e];
    int e1 = 0;
#pragma unroll
    for (int e = 1; e < NE; ++e) if (l[e] > l[e1]) e1 = e;
    int e2 = (e1 == 0) ? 1 : 0;
#pragma unroll
    for (int e = 0; e < NE; ++e) if (e != e1 && l[e] > l[e2]) e2 = e;

    double s = 0.0;
#pragma unroll
    for (int e = 0; e < NE; ++e) s += exp(l[e] - l[e1]);

    atomicAdd(&hist[e1], 1);
    atomicAdd(&hist[e2], 1);
    epair[t] = (unsigned)e1 | ((unsigned)e2 << 8);
    probs[2 * t]     = (float)(1.0 / s);
    probs[2 * t + 1] = (float)(exp(l[e2] - l[e1]) / s);
    __syncthreads();
    if (tid < NE) hists[blockIdx.x * NE + tid] = hist[tid];
}

// ===========================================================================
// Gate phase B: exclusive prefix scan of per-block histograms.
// ===========================================================================
__global__ __launch_bounds__(256) void gate_scan(
    const int* __restrict__ hists, int* __restrict__ bases, int* __restrict__ cnt) {
    __shared__ int s[256];
    const int tid = threadIdx.x;
    for (int e = 0; e < NE; ++e) {
        int v = hists[tid * NE + e];
        s[tid] = v;
        __syncthreads();
        for (int off = 1; off < 256; off <<= 1) {
            int t = (tid >= off) ? s[tid - off] : 0;
            __syncthreads();
            s[tid] += t;
            __syncthreads();
        }
        bases[tid * NE + e] = s[tid] - v;
        if (tid == 255) cnt[e] = s[255];
        __syncthreads();
    }
}

// ===========================================================================
// Gate phase C: scatter tokens into per-expert bins; record each token's two
// bin slots in opos[t] for the combine pass.
// ===========================================================================
__global__ __launch_bounds__(128) void gate_scatter(
    const unsigned* __restrict__ epair, const float* __restrict__ probs,
    const int* __restrict__ bases,
    int* __restrict__ bidx, float* __restrict__ bp, int2* __restrict__ opos) {
    __shared__ int hist[NE], bs[NE];
    const int tid = threadIdx.x;
    if (tid < NE) { hist[tid] = 0; bs[tid] = bases[blockIdx.x * NE + tid]; }
    __syncthreads();
    const int t = blockIdx.x * 128 + tid;
    const unsigned u = epair[t];
    const int e1 = u & 255, e2 = (u >> 8) & 255;
    const float p1 = probs[2 * t], p2 = probs[2 * t + 1];
    const int pos1 = atomicAdd(&hist[e1], 1);
    const int pos2 = atomicAdd(&hist[e2], 1);
    const int o1 = e1 * N_TOK + bs[e1] + pos1;
    const int o2 = e2 * N_TOK + bs[e2] + pos2;
    bidx[o1] = t;  bp[o1] = p1;
    bidx[o2] = t;  bp[o2] = p2;
    opos[t] = make_int2(o1, o2);
}

// ===========================================================================
// Expert FFN v8 = v7 with barrier semantics fixed (T3/T4/T5):
//  - raw s_barrier + lgkmcnt(0) only -> NO vmcnt drain at phase boundaries;
//    compiler's counted vmcnt for register weight-loads now spans barriers,
//    so the deep w1/w2 prefetch actually hides L2 latency.
//  - w2 (wb) issued before the pack phase (pack VALU hides its latency).
//  - s_setprio(1) around both MFMA clusters (phase role-split exists now).
//  - yp stores nontemporal (don't evict the 2MB/XCD weight set from L2).
// Layouts/math identical to verified rounds 2-7.
// ===========================================================================
__global__ __launch_bounds__(256, 2) void expert_ffn(
    const float* __restrict__ x,
    const short* __restrict__ w1f,
    const short* __restrict__ w2f,
    const float* __restrict__ b1, const float* __restrict__ b2,
    const int* __restrict__ cnt, const int* __restrict__ bidx,
    const float* __restrict__ bp, float* __restrict__ out,
    float* __restrict__ yp, int staged) {
    const int e    = blockIdx.x & 7;
    const int tile = blockIdx.x >> 3;
    const int n_e  = cnt[e];
    const int row0 = tile * TB;
    if (row0 >= n_e) return;

    __shared__ short xs[16 * 64 * 16];   // 32KB [dblk][tok][16] frag-major
    __shared__ short hs[2][16 * 512];    // 32KB dbuf [frag(fb*2+tp)][512]
    __shared__ int   tok_s[TB];
    __shared__ float p_s[TB];

    const int tid  = threadIdx.x;
    const int lane = tid & 63, wid = tid >> 6;
    const int l31  = lane & 31, g = lane >> 5;

    if (tid < TB) {
        int r = row0 + tid;
        tok_s[tid] = (r < n_e) ? bidx[e * N_TOK + r] : -1;
        p_s[tid]   = (r < n_e) ? bp[e * N_TOK + r] : 0.f;
    }
    BARRIER();

    // ---- stage x -> xs (bf16 frag-major): element (tok, d=db*16+g*8+j)
    // at xs[db*1024 + tok*16 + g*8 + j]. Invalid rows zero-filled.
    {
        const int tok = tid >> 2;
        const int tk  = tok_s[tok];
        const float* xrow = x + (size_t)(tk < 0 ? 0 : tk) * D;
#pragma unroll
        for (int i = 0; i < 4; ++i) {
            const int dblk = (tid & 3) * 4 + i;
            unsigned u[8];
            if (tk >= 0) {
#pragma unroll
                for (int q = 0; q < 4; ++q) {
                    float4 v = *(const float4*)(xrow + dblk * 16 + q * 4);
                    u[q * 2 + 0] = (unsigned)f2bf(v.x) | ((unsigned)f2bf(v.y) << 16);
                    u[q * 2 + 1] = (unsigned)f2bf(v.z) | ((unsigned)f2bf(v.w) << 16);
                }
            } else {
#pragma unroll
                for (int q = 0; q < 8; ++q) u[q] = 0;
            }
            short* dp = &xs[dblk * 1024 + tok * 16];
            *(uint4*)(dp)     = make_uint4(u[0], u[1], u[2], u[3]);
            *(uint4*)(dp + 8) = make_uint4(u[4], u[5], u[6], u[7]);
        }
    }

    f32x16 acc[2][2];   // [tp tok-half][cb col-half]
#pragma unroll
    for (int a = 0; a < 2; ++a)
#pragma unroll
        for (int b = 0; b < 2; ++b)
#pragma unroll
            for (int r = 0; r < 16; ++r) acc[a][b][r] = 0.f;

    const short* w1e = w1f + (size_t)e * (32 * 16 * 512);
    const short* w2e = w2f + (size_t)e * (8 * 64 * 512);
    const float* b1e = b1 + e * DFF;

    // ---- prologue: issue w1 low-half (db 0..7) for fc=0
    bf16x8 w1pre[8];
    {
        const short* w1p0 = w1e + ((size_t)(0 * 4 + wid) * 16) * 512 + lane * 8;
#pragma unroll
        for (int k = 0; k < 8; ++k) w1pre[k] = *(const bf16x8*)(w1p0 + k * 512);
    }

    BARRIER();   // xs ready

    for (int fc = 0; fc < 8; ++fc) {
        const short* w1c = w1e + ((size_t)(fc * 4 + wid) * 16) * 512 + lane * 8;

        // ---------- GEMM1: wave wid -> f-strip [fc*128+wid*32, +32) x 64 tok
        bf16x8 w1hi[8];
#pragma unroll
        for (int k = 0; k < 8; ++k) w1hi[k] = *(const bf16x8*)(w1c + (k + 8) * 512);

        f32x16 h0, h1;
#pragma unroll
        for (int r = 0; r < 16; ++r) { h0[r] = 0.f; h1[r] = 0.f; }

        __builtin_amdgcn_s_setprio(1);
#pragma unroll
        for (int db = 0; db < 8; ++db) {
            bf16x8 x0 = *(const bf16x8*)&xs[db * 1024 + l31 * 16 + g * 8];
            bf16x8 x1 = *(const bf16x8*)&xs[db * 1024 + 512 + l31 * 16 + g * 8];
            h0 = __builtin_amdgcn_mfma_f32_32x32x16_bf16(w1pre[db], x0, h0, 0, 0, 0);
            h1 = __builtin_amdgcn_mfma_f32_32x32x16_bf16(w1pre[db], x1, h1, 0, 0, 0);
        }
#pragma unroll
        for (int db = 0; db < 8; ++db) {
            bf16x8 x0 = *(const bf16x8*)&xs[(8 + db) * 1024 + l31 * 16 + g * 8];
            bf16x8 x1 = *(const bf16x8*)&xs[(8 + db) * 1024 + 512 + l31 * 16 + g * 8];
            h0 = __builtin_amdgcn_mfma_f32_32x32x16_bf16(w1hi[db], x0, h0, 0, 0, 0);
            h1 = __builtin_amdgcn_mfma_f32_32x32x16_bf16(w1hi[db], x1, h1, 0, 0, 0);
        }
        __builtin_amdgcn_s_setprio(0);

        // ---------- issue w2 fb 0..3 (both col-halves) BEFORE pack: the
        // pack VALU + barrier hide its L2 latency.
        const short* w2p = w2e + ((size_t)(wid * 2) * 64 + fc * 8) * 512 + lane * 8;
        bf16x8 wb[4][2];
#pragma unroll
        for (int fb = 0; fb < 4; ++fb) {
            wb[fb][0] = *(const bf16x8*)(w2p + fb * 512);
            wb[fb][1] = *(const bf16x8*)(w2p + fb * 512 + (size_t)64 * 512);
        }

        // ---------- pack: bias+relu+bf16 -> hs[fc&1] frag-major
        short* hbuf = &hs[fc & 1][0];
#pragma unroll
        for (int th = 0; th < 2; ++th) {
            const f32x16& hh = th ? h1 : h0;
#pragma unroll
            for (int m = 0; m < 4; ++m) {
                float4 bq = *(const float4*)(b1e + fc * 128 + wid * 32 + 8 * m + 4 * g);
                float v0 = fmaxf(hh[4 * m + 0] + bq.x, 0.f);
                float v1 = fmaxf(hh[4 * m + 1] + bq.y, 0.f);
                float v2 = fmaxf(hh[4 * m + 2] + bq.z, 0.f);
                float v3 = fmaxf(hh[4 * m + 3] + bq.w, 0.f);
                uint2 pk;
                pk.x = (unsigned)f2bf(v0) | ((unsigned)f2bf(v1) << 16);
                pk.y = (unsigned)f2bf(v2) | ((unsigned)f2bf(v3) << 16);
                const int fragid = (2 * wid + (m >> 1)) * 2 + th;
                *(uint2*)&hbuf[fragid * 512 + ((m & 1) * 32 + l31) * 8 + 4 * g] = pk;
            }
        }

        // ---------- issue w1 low-half for fc+1 (survives the raw barrier;
        // lands during GEMM2 + next-iteration w1hi issue)
        if (fc < 7) {
            const short* w1n = w1e + ((size_t)((fc + 1) * 4 + wid) * 16) * 512 + lane * 8;
#pragma unroll
            for (int k = 0; k < 8; ++k) w1pre[k] = *(const bf16x8*)(w1n + k * 512);
        }

        BARRIER();   // hs[fc&1] ready; in-flight vmem NOT drained

        // ---------- GEMM2: wave wid -> cols [wid*64, +64), k over 128 f
        __builtin_amdgcn_s_setprio(1);
        bf16x8 wr[4][2];
#pragma unroll
        for (int fb = 0; fb < 4; ++fb) {
            bf16x8 ha0 = *(const bf16x8*)&hbuf[(fb * 2 + 0) * 512 + lane * 8];
            bf16x8 ha1 = *(const bf16x8*)&hbuf[(fb * 2 + 1) * 512 + lane * 8];
            wr[fb][0] = *(const bf16x8*)(w2p + (fb + 4) * 512);
            wr[fb][1] = *(const bf16x8*)(w2p + (fb + 4) * 512 + (size_t)64 * 512);
            acc[0][0] = __builtin_amdgcn_mfma_f32_32x32x16_bf16(ha0, wb[fb][0], acc[0][0], 0, 0, 0);
            acc[0][1] = __builtin_amdgcn_mfma_f32_32x32x16_bf16(ha0, wb[fb][1], acc[0][1], 0, 0, 0);
            acc[1][0] = __builtin_amdgcn_mfma_f32_32x32x16_bf16(ha1, wb[fb][0], acc[1][0], 0, 0, 0);
            acc[1][1] = __builtin_amdgcn_mfma_f32_32x32x16_bf16(ha1, wb[fb][1], acc[1][1], 0, 0, 0);
        }
#pragma unroll
        for (int fb = 0; fb < 4; ++fb) {
            bf16x8 ha0 = *(const bf16x8*)&hbuf[((fb + 4) * 2 + 0) * 512 + lane * 8];
            bf16x8 ha1 = *(const bf16x8*)&hbuf[((fb + 4) * 2 + 1) * 512 + lane * 8];
            acc[0][0] = __builtin_amdgcn_mfma_f32_32x32x16_bf16(ha0, wr[fb][0], acc[0][0], 0, 0, 0);
            acc[0][1] = __builtin_amdgcn_mfma_f32_32x32x16_bf16(ha0, wr[fb][1], acc[0][1], 0, 0, 0);
            acc[1][0] = __builtin_amdgcn_mfma_f32_32x32x16_bf16(ha1, wr[fb][0], acc[1][0], 0, 0, 0);
            acc[1][1] = __builtin_amdgcn_mfma_f32_32x32x16_bf16(ha1, wr[fb][1], acc[1][1], 0, 0, 0);
        }
        __builtin_amdgcn_s_setprio(0);
    }

    // ---- epilogue ----
    const float* b2e = b2 + e * D;
    if (staged) {
        // bin-contiguous nontemporal stores (keep L2 weight-resident);
        // combine() sums the two slots per token.
        float* ype = yp + ((size_t)e * N_TOK + row0) * 256;
#pragma unroll
        for (int tp = 0; tp < 2; ++tp) {
#pragma unroll
            for (int cb = 0; cb < 2; ++cb) {
                const int col = wid * 64 + cb * 32 + l31;
                const float bv = b2e[col];
#pragma unroll
                for (int r = 0; r < 16; ++r) {
                    const int tl = tp * 32 + (r & 3) + 8 * (r >> 2) + 4 * g;
                    if (tok_s[tl] >= 0)
                        __builtin_nontemporal_store(
                            (acc[tp][cb][r] + bv) * p_s[tl],
                            &ype[(size_t)tl * 256 + col]);
                }
            }
        }
    } else {
        // fallback: 2 commutative fp32 atomics per out element (zeroed buffer)
#pragma unroll
        for (int tp = 0; tp < 2; ++tp) {
#pragma unroll
            for (int cb = 0; cb < 2; ++cb) {
                const int col = wid * 64 + cb * 32 + l31;
                const float bv = b2e[col];
#pragma unroll
                for (int r = 0; r < 16; ++r) {
                    const int tl = tp * 32 + (r & 3) + 8 * (r >> 2) + 4 * g;
                    const int tk = tok_s[tl];
                    if (tk >= 0)
                        atomicAdd(out + (size_t)tk * D + col,
                                  (acc[tp][cb][r] + bv) * p_s[tl]);
                }
            }
        }
    }
}

// ===========================================================================
// Combine: out[t] = yp[o1] + yp[o2]. One wave per token row (64 lanes x
// float4 = 1KB row); opos read is wave-uniform (scalar broadcast).
// ===========================================================================
__global__ __launch_bounds__(256) void combine(
    const float* __restrict__ yp, const int2* __restrict__ opos,
    float* __restrict__ out) {
    const int gid   = blockIdx.x * 256 + threadIdx.x;  // float4 index
    const int t     = gid >> 6;
    const int lane4 = gid & 63;
    const int2 o = opos[t];
    const float4 a = ((const float4*)yp)[(size_t)o.x * 64 + lane4];
    const float4 b = ((const float4*)yp)[(size_t)o.y * 64 + lane4];
    float4 r;
    r.x = a.x + b.x; r.y = a.y + b.y; r.z = a.z + b.z; r.w = a.w + b.w;
    ((float4*)out)[gid] = r;
}

// ---------------------------------------------------------------------------
extern "C" void kernel_launch(void* const* d_in, const int* in_sizes, int n_in,
                              void* d_out, int out_size, void* d_ws, size_t ws_size,
                              hipStream_t stream) {
    const float* x  = (const float*)d_in[0];
    const float* gw = (const float*)d_in[1];
    const float* gb = (const float*)d_in[2];
    const float* w1 = (const float*)d_in[3];
    const float* b1 = (const float*)d_in[4];
    const float* w2 = (const float*)d_in[5];
    const float* b2 = (const float*)d_in[6];
    float* out = (float*)d_out;

    // ws: cnt 256B | bidx 1MB | bp 1MB | opos 512KB | w1f 4MB | w2f 4MB
    //   | yp 64MB (staged partials).  Gate temporaries alias w1f (consumed
    //   before w1f_prep; stream-ordered).
    char* ws = (char*)d_ws;
    size_t off = 0;
    int*   cnt   = (int*)(ws + off);  off += 256;
    int*   bidx  = (int*)(ws + off);  off += (size_t)NE * N_TOK * 4;
    float* bp    = (float*)(ws + off); off += (size_t)NE * N_TOK * 4;
    int2*  opos  = (int2*)(ws + off); off += (size_t)N_TOK * 8;
    short* w1f   = (short*)(ws + off); off += (size_t)NE * D * DFF * 2;
    short* w2f   = (short*)(ws + off); off += (size_t)NE * D * DFF * 2;
    float* yp    = (float*)(ws + off); off += (size_t)2 * N_TOK * D * 4;
    const int staged = (ws_size >= off) ? 1 : 0;

    unsigned* epair = (unsigned*)w1f;                       // 128KB
    float*    probs = (float*)((char*)w1f + (128 << 10));   // 256KB
    int*      hists = (int*)((char*)w1f + (384 << 10));     // 8KB
    int*      bases = (int*)((char*)w1f + (392 << 10));     // 8KB

    if (!staged)
        hipMemsetAsync(d_out, 0, (size_t)out_size * sizeof(float), stream);

    gate_compute<<<N_TOK / 128, 128, 0, stream>>>(x, gw, gb, epair, probs, hists);
    gate_scan<<<1, 256, 0, stream>>>(hists, bases, cnt);
    gate_scatter<<<N_TOK / 128, 128, 0, stream>>>(epair, probs, bases, bidx, bp, opos);
    w1f_prep<<<1024, 256, 0, stream>>>(w1, w1f);
    w2f_prep<<<1024, 256, 0, stream>>>(w2, w2f);
    expert_ffn<<<NE * (N_TOK / TB), 256, 0, stream>>>(x, w1f, w2f, b1, b2,
                                                      cnt, bidx, bp, out, yp, staged);
    if (staged)
        combine<<<(N_TOK * D / 4) / 256, 256, 0, stream>>>(yp, opos, out);
}

// Round 9
// 166.798 us; speedup vs baseline: 1.2079x; 1.0766x over previous
//
#include <hip/hip_runtime.h>

#define N_TOK 32768
#define D 256
#define DFF 1024
#define NE 8
#define TB 64    // tokens per expert_ffn block

typedef __attribute__((ext_vector_type(16))) float f32x16;
typedef __attribute__((ext_vector_type(8)))  short bf16x8;

// Raw barrier: LDS writes made visible (lgkmcnt(0)) but NO vmcnt drain --
// in-flight global weight loads survive the barrier (T3/T4; verified +13us
// in round 8).
#define BARRIER() do {                                        \
    asm volatile("s_waitcnt lgkmcnt(0)" ::: "memory");        \
    __builtin_amdgcn_s_barrier();                             \
    __builtin_amdgcn_sched_barrier(0);                        \
} while (0)

// fp32 -> bf16 round-to-nearest-even
__device__ __forceinline__ unsigned short f2bf(float f) {
    union { float f; unsigned u; } v; v.f = f;
    unsigned r = v.u + 0x7FFFu + ((v.u >> 16) & 1u);
    return (unsigned short)(r >> 16);
}

// ===========================================================================
// Fused prepass (1 launch): blocks [0,1024) do w1, [1024,2048) do w2.
// w1 [E][256 d][1024 f] fp32 -> frag-major bf16 (GEMM1-A):
//   frag=(e*32+fblk)*16+dblk; elem: f=fblk*32+(l&31), d=dblk*16+(l>>5)*8+j.
// w2 [E][1024 f][256 col] fp32 -> frag-major bf16 (GEMM2-B):
//   frag=(e*8+cblk)*64+fblk; elem: col=cblk*32+(l&31), f=fblk*16+(l>>5)*8+j.
// (conventions verified rounds 2-8)
// ===========================================================================
__global__ __launch_bounds__(256) void wf_prep(
    const float* __restrict__ w1, const float* __restrict__ w2,
    short* __restrict__ w1f, short* __restrict__ w2f) {
    const int b = blockIdx.x;
    if (b < 1024) {
        const int gid  = b * 256 + threadIdx.x;
        const int lane = gid & 63;
        const int frag = gid >> 6;
        const int dblk = frag & 15;
        const int fblk = (frag >> 4) & 31;
        const int e    = frag >> 9;
        const int l31 = lane & 31, g = lane >> 5;

        const float* src = w1 + ((size_t)e * 256 + dblk * 16 + g * 8) * 1024
                              + fblk * 32 + l31;
        unsigned u[4];
#pragma unroll
        for (int jp = 0; jp < 4; ++jp) {
            float a = src[(size_t)(jp * 2)     * 1024];
            float c = src[(size_t)(jp * 2 + 1) * 1024];
            u[jp] = (unsigned)f2bf(a) | ((unsigned)f2bf(c) << 16);
        }
        *(uint4*)(w1f + (size_t)gid * 8) = make_uint4(u[0], u[1], u[2], u[3]);
    } else {
        const int gid  = (b - 1024) * 256 + threadIdx.x;
        const int lane = gid & 63;
        const int frag = gid >> 6;
        const int fblk = frag & 63;
        const int cblk = (frag >> 6) & 7;
        const int e    = frag >> 9;
        const int l31 = lane & 31, g = lane >> 5;

        const float* src = w2 + ((size_t)e * 1024 + fblk * 16 + g * 8) * 256
                              + cblk * 32 + l31;
        unsigned u[4];
#pragma unroll
        for (int jp = 0; jp < 4; ++jp) {
            float a = src[(size_t)(jp * 2)     * 256];
            float c = src[(size_t)(jp * 2 + 1) * 256];
            u[jp] = (unsigned)f2bf(a) | ((unsigned)f2bf(c) << 16);
        }
        *(uint4*)(w2f + (size_t)gid * 8) = make_uint4(u[0], u[1], u[2], u[3]);
    }
}

// ===========================================================================
// Gate (single kernel, round-3 proven design + opos): thread-per-token fp64
// logits, top-2, softmax; LDS histogram -> 8 global atomics/block -> scatter.
// Bin ORDER may vary run-to-run but per-token partials are position-invariant
// (same op sequence for every tile row), so out is bitwise deterministic.
// ===========================================================================
__global__ __launch_bounds__(256) void gate_all(
    const float* __restrict__ x, const float* __restrict__ gw,
    const float* __restrict__ gb,
    int* __restrict__ cnt, int* __restrict__ bidx, float* __restrict__ bp,
    int2* __restrict__ opos) {
    __shared__ float gws[2048];   // [d][e]
    __shared__ int   se1[256], se2[256];
    __shared__ float sp1[256], sp2[256];
    __shared__ int   hist[NE], base_[NE];

    const int tid = threadIdx.x;
#pragma unroll
    for (int i = 0; i < 8; ++i) gws[tid + 256 * i] = gw[tid + 256 * i];
    if (tid < NE) hist[tid] = 0;
    __syncthreads();

    const int t = blockIdx.x * 256 + tid;
    const float* xr = x + (size_t)t * D;

    double acc[NE];
#pragma unroll
    for (int e = 0; e < NE; ++e) acc[e] = 0.0;

    for (int d0 = 0; d0 < 256; d0 += 4) {
        float4 xv = *(const float4*)(xr + d0);
        float xa[4] = {xv.x, xv.y, xv.z, xv.w};
#pragma unroll
        for (int j = 0; j < 4; ++j) {
            float4 ga  = *(const float4*)&gws[(d0 + j) * 8];
            float4 gbb = *(const float4*)&gws[(d0 + j) * 8 + 4];
            double xd = (double)xa[j];
            acc[0] += xd * (double)ga.x;  acc[1] += xd * (double)ga.y;
            acc[2] += xd * (double)ga.z;  acc[3] += xd * (double)ga.w;
            acc[4] += xd * (double)gbb.x; acc[5] += xd * (double)gbb.y;
            acc[6] += xd * (double)gbb.z; acc[7] += xd * (double)gbb.w;
        }
    }

    double l[NE];
#pragma unroll
    for (int e = 0; e < NE; ++e) l[e] = acc[e] + (double)gb[e];
    int e1 = 0;
#pragma unroll
    for (int e = 1; e < NE; ++e) if (l[e] > l[e1]) e1 = e;
    int e2 = (e1 == 0) ? 1 : 0;
#pragma unroll
    for (int e = 0; e < NE; ++e) if (e != e1 && l[e] > l[e2]) e2 = e;

    double s = 0.0;
#pragma unroll
    for (int e = 0; e < NE; ++e) s += exp(l[e] - l[e1]);
    se1[tid] = e1; se2[tid] = e2;
    sp1[tid] = (float)(1.0 / s);
    sp2[tid] = (float)(exp(l[e2] - l[e1]) / s);
    __syncthreads();

    const int pos1 = atomicAdd(&hist[se1[tid]], 1);
    const int pos2 = atomicAdd(&hist[se2[tid]], 1);
    __syncthreads();
    if (tid < NE) base_[tid] = atomicAdd(&cnt[tid], hist[tid]);
    __syncthreads();

    const int o1 = se1[tid] * N_TOK + base_[se1[tid]] + pos1;
    const int o2 = se2[tid] * N_TOK + base_[se2[tid]] + pos2;
    bidx[o1] = t;  bp[o1] = sp1[tid];
    bidx[o2] = t;  bp[o2] = sp2[tid];
    opos[t] = make_int2(o1, o2);
}

// ===========================================================================
// Expert FFN v9 = v8 + explicit 2-deep register double-buffer on ALL LDS
// fragment reads (GEMM1 x-frags, GEMM2 h-frags): the ds_read for step i+2
// issues before step i's MFMA waits, so ~120cyc LDS latency pipelines at
// ~12cyc throughput (this was the residual stall: MfmaUtil 23%, 50%
// unattributed). w1-next issued before pack (longer lead). Raw barriers
// (no vmcnt drain) + setprio retained from v8. Layouts verified rounds 2-8.
// ===========================================================================
__global__ __launch_bounds__(256, 2) void expert_ffn(
    const float* __restrict__ x,
    const short* __restrict__ w1f,
    const short* __restrict__ w2f,
    const float* __restrict__ b1, const float* __restrict__ b2,
    const int* __restrict__ cnt, const int* __restrict__ bidx,
    const float* __restrict__ bp, float* __restrict__ out,
    float* __restrict__ yp, int staged) {
    const int e    = blockIdx.x & 7;
    const int tile = blockIdx.x >> 3;
    const int n_e  = cnt[e];
    const int row0 = tile * TB;
    if (row0 >= n_e) return;

    __shared__ short xs[16 * 64 * 16];   // 32KB [dblk][tok][16] frag-major
    __shared__ short hs[2][16 * 512];    // 32KB dbuf [frag(fb*2+tp)][512]
    __shared__ int   tok_s[TB];
    __shared__ float p_s[TB];

    const int tid  = threadIdx.x;
    const int lane = tid & 63, wid = tid >> 6;
    const int l31  = lane & 31, g = lane >> 5;

    if (tid < TB) {
        int r = row0 + tid;
        tok_s[tid] = (r < n_e) ? bidx[e * N_TOK + r] : -1;
        p_s[tid]   = (r < n_e) ? bp[e * N_TOK + r] : 0.f;
    }
    BARRIER();

    // ---- stage x -> xs (bf16 frag-major): element (tok, d=db*16+g*8+j)
    // at xs[db*1024 + tok*16 + g*8 + j]. Invalid rows zero-filled.
    {
        const int tok = tid >> 2;
        const int tk  = tok_s[tok];
        const float* xrow = x + (size_t)(tk < 0 ? 0 : tk) * D;
#pragma unroll
        for (int i = 0; i < 4; ++i) {
            const int dblk = (tid & 3) * 4 + i;
            unsigned u[8];
            if (tk >= 0) {
#pragma unroll
                for (int q = 0; q < 4; ++q) {
                    float4 v = *(const float4*)(xrow + dblk * 16 + q * 4);
                    u[q * 2 + 0] = (unsigned)f2bf(v.x) | ((unsigned)f2bf(v.y) << 16);
                    u[q * 2 + 1] = (unsigned)f2bf(v.z) | ((unsigned)f2bf(v.w) << 16);
                }
            } else {
#pragma unroll
                for (int q = 0; q < 8; ++q) u[q] = 0;
            }
            short* dp = &xs[dblk * 1024 + tok * 16];
            *(uint4*)(dp)     = make_uint4(u[0], u[1], u[2], u[3]);
            *(uint4*)(dp + 8) = make_uint4(u[4], u[5], u[6], u[7]);
        }
    }

    f32x16 acc[2][2];   // [tp tok-half][cb col-half]
#pragma unroll
    for (int a = 0; a < 2; ++a)
#pragma unroll
        for (int b = 0; b < 2; ++b)
#pragma unroll
            for (int r = 0; r < 16; ++r) acc[a][b][r] = 0.f;

    const short* w1e = w1f + (size_t)e * (32 * 16 * 512);
    const short* w2e = w2f + (size_t)e * (8 * 64 * 512);
    const float* b1e = b1 + e * DFF;

    // ---- prologue: issue w1 low-half (db 0..7) for fc=0
    bf16x8 w1pre[8];
    {
        const short* w1p0 = w1e + ((size_t)(0 * 4 + wid) * 16) * 512 + lane * 8;
#pragma unroll
        for (int k = 0; k < 8; ++k) w1pre[k] = *(const bf16x8*)(w1p0 + k * 512);
    }

    BARRIER();   // xs ready

    for (int fc = 0; fc < 8; ++fc) {
        const short* w1c = w1e + ((size_t)(fc * 4 + wid) * 16) * 512 + lane * 8;

        // ---------- GEMM1: wave wid -> f-strip [fc*128+wid*32, +32) x 64 tok
        bf16x8 w1hi[8];
#pragma unroll
        for (int k = 0; k < 8; ++k) w1hi[k] = *(const bf16x8*)(w1c + (k + 8) * 512);

        f32x16 h0, h1;
#pragma unroll
        for (int r = 0; r < 16; ++r) { h0[r] = 0.f; h1[r] = 0.f; }

        __builtin_amdgcn_s_setprio(1);
        {
            // 2-deep register double-buffer on xs reads
            bf16x8 xc0 = *(const bf16x8*)&xs[l31 * 16 + g * 8];
            bf16x8 xc1 = *(const bf16x8*)&xs[512 + l31 * 16 + g * 8];
            bf16x8 xn0 = *(const bf16x8*)&xs[1024 + l31 * 16 + g * 8];
            bf16x8 xn1 = *(const bf16x8*)&xs[1024 + 512 + l31 * 16 + g * 8];
#pragma unroll
            for (int db = 0; db < 16; ++db) {
                bf16x8 f0 = xc0, f1 = xc1;
                xc0 = xn0; xc1 = xn1;
                if (db < 14) {
                    xn0 = *(const bf16x8*)&xs[(db + 2) * 1024 + l31 * 16 + g * 8];
                    xn1 = *(const bf16x8*)&xs[(db + 2) * 1024 + 512 + l31 * 16 + g * 8];
                }
                const bf16x8 w = (db < 8) ? w1pre[db] : w1hi[db - 8];
                h0 = __builtin_amdgcn_mfma_f32_32x32x16_bf16(w, f0, h0, 0, 0, 0);
                h1 = __builtin_amdgcn_mfma_f32_32x32x16_bf16(w, f1, h1, 0, 0, 0);
            }
        }
        __builtin_amdgcn_s_setprio(0);

        // ---------- issue w2 fb 0..3 (both col-halves): consumed right after
        // the barrier; pack VALU + barrier hide the L2 latency.
        const short* w2p = w2e + ((size_t)(wid * 2) * 64 + fc * 8) * 512 + lane * 8;
        bf16x8 wb[4][2];
#pragma unroll
        for (int fb = 0; fb < 4; ++fb) {
            wb[fb][0] = *(const bf16x8*)(w2p + fb * 512);
            wb[fb][1] = *(const bf16x8*)(w2p + fb * 512 + (size_t)64 * 512);
        }

        // ---------- issue w1 low-half for fc+1 (lands during pack + barrier
        // + GEMM2; survives the raw barrier — no vmcnt drain)
        if (fc < 7) {
            const short* w1n = w1e + ((size_t)((fc + 1) * 4 + wid) * 16) * 512 + lane * 8;
#pragma unroll
            for (int k = 0; k < 8; ++k) w1pre[k] = *(const bf16x8*)(w1n + k * 512);
        }

        // ---------- pack: bias+relu+bf16 -> hs[fc&1] frag-major
        short* hbuf = &hs[fc & 1][0];
#pragma unroll
        for (int th = 0; th < 2; ++th) {
            const f32x16& hh = th ? h1 : h0;
#pragma unroll
            for (int m = 0; m < 4; ++m) {
                float4 bq = *(const float4*)(b1e + fc * 128 + wid * 32 + 8 * m + 4 * g);
                float v0 = fmaxf(hh[4 * m + 0] + bq.x, 0.f);
                float v1 = fmaxf(hh[4 * m + 1] + bq.y, 0.f);
                float v2 = fmaxf(hh[4 * m + 2] + bq.z, 0.f);
                float v3 = fmaxf(hh[4 * m + 3] + bq.w, 0.f);
                uint2 pk;
                pk.x = (unsigned)f2bf(v0) | ((unsigned)f2bf(v1) << 16);
                pk.y = (unsigned)f2bf(v2) | ((unsigned)f2bf(v3) << 16);
                const int fragid = (2 * wid + (m >> 1)) * 2 + th;
                *(uint2*)&hbuf[fragid * 512 + ((m & 1) * 32 + l31) * 8 + 4 * g] = pk;
            }
        }

        BARRIER();   // hs[fc&1] ready; in-flight vmem NOT drained

        // ---------- GEMM2: wave wid -> cols [wid*64, +64), k over 128 f
        __builtin_amdgcn_s_setprio(1);
        {
            // 2-deep register double-buffer on hs reads; wr rolls 4 ahead
            bf16x8 hc0 = *(const bf16x8*)&hbuf[0 * 512 + lane * 8];
            bf16x8 hc1 = *(const bf16x8*)&hbuf[1 * 512 + lane * 8];
            bf16x8 wr[4][2];
#pragma unroll
            for (int fb = 0; fb < 8; ++fb) {
                bf16x8 a0 = hc0, a1 = hc1;
                if (fb < 7) {
                    hc0 = *(const bf16x8*)&hbuf[(2 * fb + 2) * 512 + lane * 8];
                    hc1 = *(const bf16x8*)&hbuf[(2 * fb + 3) * 512 + lane * 8];
                }
                bf16x8 wA, wB;
                if (fb < 4) {
                    wA = wb[fb][0]; wB = wb[fb][1];
                    wr[fb][0] = *(const bf16x8*)(w2p + (fb + 4) * 512);
                    wr[fb][1] = *(const bf16x8*)(w2p + (fb + 4) * 512 + (size_t)64 * 512);
                } else {
                    wA = wr[fb - 4][0]; wB = wr[fb - 4][1];
                }
                acc[0][0] = __builtin_amdgcn_mfma_f32_32x32x16_bf16(a0, wA, acc[0][0], 0, 0, 0);
                acc[0][1] = __builtin_amdgcn_mfma_f32_32x32x16_bf16(a0, wB, acc[0][1], 0, 0, 0);
                acc[1][0] = __builtin_amdgcn_mfma_f32_32x32x16_bf16(a1, wA, acc[1][0], 0, 0, 0);
                acc[1][1] = __builtin_amdgcn_mfma_f32_32x32x16_bf16(a1, wB, acc[1][1], 0, 0, 0);
            }
        }
        __builtin_amdgcn_s_setprio(0);
    }

    // ---- epilogue ----
    const float* b2e = b2 + e * D;
    if (staged) {
        // bin-contiguous nontemporal stores (keep L2 weight-resident);
        // combine() sums the two slots per token.
        float* ype = yp + ((size_t)e * N_TOK + row0) * 256;
#pragma unroll
        for (int tp = 0; tp < 2; ++tp) {
#pragma unroll
            for (int cb = 0; cb < 2; ++cb) {
                const int col = wid * 64 + cb * 32 + l31;
                const float bv = b2e[col];
#pragma unroll
                for (int r = 0; r < 16; ++r) {
                    const int tl = tp * 32 + (r & 3) + 8 * (r >> 2) + 4 * g;
                    if (tok_s[tl] >= 0)
                        __builtin_nontemporal_store(
                            (acc[tp][cb][r] + bv) * p_s[tl],
                            &ype[(size_t)tl * 256 + col]);
                }
            }
        }
    } else {
        // fallback: 2 commutative fp32 atomics per out element (zeroed buffer)
#pragma unroll
        for (int tp = 0; tp < 2; ++tp) {
#pragma unroll
            for (int cb = 0; cb < 2; ++cb) {
                const int col = wid * 64 + cb * 32 + l31;
                const float bv = b2e[col];
#pragma unroll
                for (int r = 0; r < 16; ++r) {
                    const int tl = tp * 32 + (r & 3) + 8 * (r >> 2) + 4 * g;
                    const int tk = tok_s[tl];
                    if (tk >= 0)
                        atomicAdd(out + (size_t)tk * D + col,
                                  (acc[tp][cb][r] + bv) * p_s[tl]);
                }
            }
        }
    }
}

// ===========================================================================
// Combine: out[t] = yp[o1] + yp[o2]. One wave per token row (64 lanes x
// float4 = 1KB row); opos read is wave-uniform (scalar broadcast).
// ===========================================================================
__global__ __launch_bounds__(256) void combine(
    const float* __restrict__ yp, const int2* __restrict__ opos,
    float* __restrict__ out) {
    const int gid   = blockIdx.x * 256 + threadIdx.x;  // float4 index
    const int t     = gid >> 6;
    const int lane4 = gid & 63;
    const int2 o = opos[t];
    const float4 a = ((const float4*)yp)[(size_t)o.x * 64 + lane4];
    const float4 b = ((const float4*)yp)[(size_t)o.y * 64 + lane4];
    float4 r;
    r.x = a.x + b.x; r.y = a.y + b.y; r.z = a.z + b.z; r.w = a.w + b.w;
    ((float4*)out)[gid] = r;
}

// ---------------------------------------------------------------------------
extern "C" void kernel_launch(void* const* d_in, const int* in_sizes, int n_in,
                              void* d_out, int out_size, void* d_ws, size_t ws_size,
                              hipStream_t stream) {
    const float* x  = (const float*)d_in[0];
    const float* gw = (const float*)d_in[1];
    const float* gb = (const float*)d_in[2];
    const float* w1 = (const float*)d_in[3];
    const float* b1 = (const float*)d_in[4];
    const float* w2 = (const float*)d_in[5];
    const float* b2 = (const float*)d_in[6];
    float* out = (float*)d_out;

    // ws: cnt 256B | bidx 1MB | bp 1MB | opos 512KB | w1f 4MB | w2f 4MB
    //   | yp 64MB (staged partials).
    char* ws = (char*)d_ws;
    size_t off = 0;
    int*   cnt   = (int*)(ws + off);  off += 256;
    int*   bidx  = (int*)(ws + off);  off += (size_t)NE * N_TOK * 4;
    float* bp    = (float*)(ws + off); off += (size_t)NE * N_TOK * 4;
    int2*  opos  = (int2*)(ws + off); off += (size_t)N_TOK * 8;
    short* w1f   = (short*)(ws + off); off += (size_t)NE * D * DFF * 2;
    short* w2f   = (short*)(ws + off); off += (size_t)NE * D * DFF * 2;
    float* yp    = (float*)(ws + off); off += (size_t)2 * N_TOK * D * 4;
    const int staged = (ws_size >= off) ? 1 : 0;

    hipMemsetAsync(cnt, 0, 256, stream);
    if (!staged)
        hipMemsetAsync(d_out, 0, (size_t)out_size * sizeof(float), stream);

    gate_all<<<N_TOK / 256, 256, 0, stream>>>(x, gw, gb, cnt, bidx, bp, opos);
    wf_prep<<<2048, 256, 0, stream>>>(w1, w2, w1f, w2f);
    expert_ffn<<<NE * (N_TOK / TB), 256, 0, stream>>>(x, w1f, w2f, b1, b2,
                                                      cnt, bidx, bp, out, yp, staged);
    if (staged)
        combine<<<(N_TOK * D / 4) / 256, 256, 0, stream>>>(yp, opos, out);
}

// Round 10
// 159.881 us; speedup vs baseline: 1.2602x; 1.0433x over previous
//
#include <hip/hip_runtime.h>

#define N_TOK 32768
#define D 256
#define DFF 1024
#define NE 8
#define TB 64    // tokens per expert_ffn block

typedef __attribute__((ext_vector_type(16))) float f32x16;
typedef __attribute__((ext_vector_type(8)))  short bf16x8;

// Raw barrier: LDS writes made visible (lgkmcnt(0)) but NO vmcnt drain --
// in-flight global weight loads survive the barrier (T3/T4; verified r8).
#define BARRIER() do {                                        \
    asm volatile("s_waitcnt lgkmcnt(0)" ::: "memory");        \
    __builtin_amdgcn_s_barrier();                             \
    __builtin_amdgcn_sched_barrier(0);                        \
} while (0)

// fp32 -> bf16 round-to-nearest-even
__device__ __forceinline__ unsigned short f2bf(float f) {
    union { float f; unsigned u; } v; v.f = f;
    unsigned r = v.u + 0x7FFFu + ((v.u >> 16) & 1u);
    return (unsigned short)(r >> 16);
}

// ===========================================================================
// Fused prepass (1 launch): blocks [0,1024) do w1, [1024,2048) do w2.
// w1 [E][256 d][1024 f] fp32 -> frag-major bf16 (GEMM1-A):
//   frag=(e*32+fblk)*16+dblk; elem: f=fblk*32+(l&31), d=dblk*16+(l>>5)*8+j.
// w2 [E][1024 f][256 col] fp32 -> frag-major bf16 (GEMM2-B):
//   frag=(e*8+cblk)*64+fblk; elem: col=cblk*32+(l&31), f=fblk*16+(l>>5)*8+j.
// (conventions verified rounds 2-9)
// ===========================================================================
__global__ __launch_bounds__(256) void wf_prep(
    const float* __restrict__ w1, const float* __restrict__ w2,
    short* __restrict__ w1f, short* __restrict__ w2f) {
    const int b = blockIdx.x;
    if (b < 1024) {
        const int gid  = b * 256 + threadIdx.x;
        const int lane = gid & 63;
        const int frag = gid >> 6;
        const int dblk = frag & 15;
        const int fblk = (frag >> 4) & 31;
        const int e    = frag >> 9;
        const int l31 = lane & 31, g = lane >> 5;

        const float* src = w1 + ((size_t)e * 256 + dblk * 16 + g * 8) * 1024
                              + fblk * 32 + l31;
        unsigned u[4];
#pragma unroll
        for (int jp = 0; jp < 4; ++jp) {
            float a = src[(size_t)(jp * 2)     * 1024];
            float c = src[(size_t)(jp * 2 + 1) * 1024];
            u[jp] = (unsigned)f2bf(a) | ((unsigned)f2bf(c) << 16);
        }
        *(uint4*)(w1f + (size_t)gid * 8) = make_uint4(u[0], u[1], u[2], u[3]);
    } else {
        const int gid  = (b - 1024) * 256 + threadIdx.x;
        const int lane = gid & 63;
        const int frag = gid >> 6;
        const int fblk = frag & 63;
        const int cblk = (frag >> 6) & 7;
        const int e    = frag >> 9;
        const int l31 = lane & 31, g = lane >> 5;

        const float* src = w2 + ((size_t)e * 1024 + fblk * 16 + g * 8) * 256
                              + cblk * 32 + l31;
        unsigned u[4];
#pragma unroll
        for (int jp = 0; jp < 4; ++jp) {
            float a = src[(size_t)(jp * 2)     * 256];
            float c = src[(size_t)(jp * 2 + 1) * 256];
            u[jp] = (unsigned)f2bf(a) | ((unsigned)f2bf(c) << 16);
        }
        *(uint4*)(w2f + (size_t)gid * 8) = make_uint4(u[0], u[1], u[2], u[3]);
    }
}

// ===========================================================================
// Gate (single kernel): thread-per-token fp64 logits, top-2, softmax;
// LDS histogram -> 8 global atomics/block -> scatter; opos for combine.
// ===========================================================================
__global__ __launch_bounds__(256) void gate_all(
    const float* __restrict__ x, const float* __restrict__ gw,
    const float* __restrict__ gb,
    int* __restrict__ cnt, int* __restrict__ bidx, float* __restrict__ bp,
    int2* __restrict__ opos) {
    __shared__ float gws[2048];   // [d][e]
    __shared__ int   se1[256], se2[256];
    __shared__ float sp1[256], sp2[256];
    __shared__ int   hist[NE], base_[NE];

    const int tid = threadIdx.x;
#pragma unroll
    for (int i = 0; i < 8; ++i) gws[tid + 256 * i] = gw[tid + 256 * i];
    if (tid < NE) hist[tid] = 0;
    __syncthreads();

    const int t = blockIdx.x * 256 + tid;
    const float* xr = x + (size_t)t * D;

    double acc[NE];
#pragma unroll
    for (int e = 0; e < NE; ++e) acc[e] = 0.0;

    for (int d0 = 0; d0 < 256; d0 += 4) {
        float4 xv = *(const float4*)(xr + d0);
        float xa[4] = {xv.x, xv.y, xv.z, xv.w};
#pragma unroll
        for (int j = 0; j < 4; ++j) {
            float4 ga  = *(const float4*)&gws[(d0 + j) * 8];
            float4 gbb = *(const float4*)&gws[(d0 + j) * 8 + 4];
            double xd = (double)xa[j];
            acc[0] += xd * (double)ga.x;  acc[1] += xd * (double)ga.y;
            acc[2] += xd * (double)ga.z;  acc[3] += xd * (double)ga.w;
            acc[4] += xd * (double)gbb.x; acc[5] += xd * (double)gbb.y;
            acc[6] += xd * (double)gbb.z; acc[7] += xd * (double)gbb.w;
        }
    }

    double l[NE];
#pragma unroll
    for (int e = 0; e < NE; ++e) l[e] = acc[e] + (double)gb[e];
    int e1 = 0;
#pragma unroll
    for (int e = 1; e < NE; ++e) if (l[e] > l[e1]) e1 = e;
    int e2 = (e1 == 0) ? 1 : 0;
#pragma unroll
    for (int e = 0; e < NE; ++e) if (e != e1 && l[e] > l[e2]) e2 = e;

    double s = 0.0;
#pragma unroll
    for (int e = 0; e < NE; ++e) s += exp(l[e] - l[e1]);
    se1[tid] = e1; se2[tid] = e2;
    sp1[tid] = (float)(1.0 / s);
    sp2[tid] = (float)(exp(l[e2] - l[e1]) / s);
    __syncthreads();

    const int pos1 = atomicAdd(&hist[se1[tid]], 1);
    const int pos2 = atomicAdd(&hist[se2[tid]], 1);
    __syncthreads();
    if (tid < NE) base_[tid] = atomicAdd(&cnt[tid], hist[tid]);
    __syncthreads();

    const int o1 = se1[tid] * N_TOK + base_[se1[tid]] + pos1;
    const int o2 = se2[tid] * N_TOK + base_[se2[tid]] + pos2;
    bidx[o1] = t;  bp[o1] = sp1[tid];
    bidx[o2] = t;  bp[o2] = sp2[tid];
    opos[t] = make_int2(o1, o2);
}

// ===========================================================================
// Expert FFN v10: 512 threads / 8 waves, TB=64, fchunk=256 (4 iters).
// RE-GEOMETRY to cross the 128-VGPR occupancy cliff (m69: waves/SIMD halve
// at 128 regs): wave wid owns a 32-f GEMM1 strip AND a 32-col GEMM2 strip,
// so acc = 2 x f32x16 (32) + hacc 2 x f32x16 (32); total regs <= 128
// (__launch_bounds__(512,4)) -> 4 waves/SIMD. LDS 64.8 KB -> 2 blocks/CU
// -> 16 waves/CU (50% occupancy, ~3x v9). 2 raw barriers per fchunk (8
// total). Zero weight redundancy (1 MB L2 per block). Fragment layouts,
// pack formula, epilogue mapping verbatim from verified rounds 2-9.
// ===========================================================================
__global__ __launch_bounds__(512, 4) void expert_ffn(
    const float* __restrict__ x,
    const short* __restrict__ w1f,
    const short* __restrict__ w2f,
    const float* __restrict__ b1, const float* __restrict__ b2,
    const int* __restrict__ cnt, const int* __restrict__ bidx,
    const float* __restrict__ bp, float* __restrict__ out,
    float* __restrict__ yp, int staged) {
    const int e    = blockIdx.x & 7;
    const int tile = blockIdx.x >> 3;
    const int n_e  = cnt[e];
    const int row0 = tile * TB;
    if (row0 >= n_e) return;

    __shared__ short xs[16 * 64 * 16];   // 32KB [dblk][tok64][16] frag-major
    __shared__ short hs[32 * 512];       // 32KB [frag(kt*2+tp)][512]
    __shared__ int   tok_s[TB];
    __shared__ float p_s[TB];

    const int tid  = threadIdx.x;
    const int lane = tid & 63, wid = tid >> 6;   // wid 0..7
    const int l31  = lane & 31, g = lane >> 5;

    if (tid < TB) {
        int r = row0 + tid;
        tok_s[tid] = (r < n_e) ? bidx[e * N_TOK + r] : -1;
        p_s[tid]   = (r < n_e) ? bp[e * N_TOK + r] : 0.f;
    }
    BARRIER();

    // ---- stage x -> xs (bf16 frag-major): element (tok, d=db*16+g*8+j)
    // at xs[db*1024 + tok*16 + g*8 + j]. 512 thr: tok=tid>>3, 2 dblks each.
    {
        const int tok = tid >> 3;
        const int tk  = tok_s[tok];
        const float* xrow = x + (size_t)(tk < 0 ? 0 : tk) * D;
#pragma unroll
        for (int i = 0; i < 2; ++i) {
            const int dblk = (tid & 7) * 2 + i;
            unsigned u[8];
            if (tk >= 0) {
#pragma unroll
                for (int q = 0; q < 4; ++q) {
                    float4 v = *(const float4*)(xrow + dblk * 16 + q * 4);
                    u[q * 2 + 0] = (unsigned)f2bf(v.x) | ((unsigned)f2bf(v.y) << 16);
                    u[q * 2 + 1] = (unsigned)f2bf(v.z) | ((unsigned)f2bf(v.w) << 16);
                }
            } else {
#pragma unroll
                for (int q = 0; q < 8; ++q) u[q] = 0;
            }
            short* dp = &xs[dblk * 1024 + tok * 16];
            *(uint4*)(dp)     = make_uint4(u[0], u[1], u[2], u[3]);
            *(uint4*)(dp + 8) = make_uint4(u[4], u[5], u[6], u[7]);
        }
    }

    f32x16 acc[2];   // [tp tok-half], cols wid*32 + l31
#pragma unroll
    for (int a = 0; a < 2; ++a)
#pragma unroll
        for (int r = 0; r < 16; ++r) acc[a][r] = 0.f;

    const short* w1e = w1f + (size_t)e * (32 * 16 * 512);
    const short* w2e = w2f + (size_t)e * (8 * 64 * 512);
    const float* b1e = b1 + e * DFF;

    BARRIER();   // xs ready

    for (int fc = 0; fc < 4; ++fc) {
        // ---------- GEMM1: wave wid -> f-strip [fc*256+wid*32, +32) x 64 tok
        f32x16 h0, h1;
#pragma unroll
        for (int r = 0; r < 16; ++r) { h0[r] = 0.f; h1[r] = 0.f; }

        const short* w1p = w1e + ((size_t)(fc * 8 + wid) * 16) * 512 + lane * 8;
        __builtin_amdgcn_s_setprio(1);
        {
            bf16x8 a0 = *(const bf16x8*)(w1p);
            bf16x8 x0 = *(const bf16x8*)&xs[l31 * 16 + g * 8];
            bf16x8 x1 = *(const bf16x8*)&xs[512 + l31 * 16 + g * 8];
#pragma unroll
            for (int db = 0; db < 16; ++db) {
                bf16x8 an, y0, y1;
                if (db < 15) {
                    an = *(const bf16x8*)(w1p + (db + 1) * 512);
                    y0 = *(const bf16x8*)&xs[(db + 1) * 1024 + l31 * 16 + g * 8];
                    y1 = *(const bf16x8*)&xs[(db + 1) * 1024 + 512 + l31 * 16 + g * 8];
                }
                h0 = __builtin_amdgcn_mfma_f32_32x32x16_bf16(a0, x0, h0, 0, 0, 0);
                h1 = __builtin_amdgcn_mfma_f32_32x32x16_bf16(a0, x1, h1, 0, 0, 0);
                if (db < 15) { a0 = an; x0 = y0; x1 = y1; }
            }
        }
        __builtin_amdgcn_s_setprio(0);

        BARRIER();   // prev GEMM2 hs reads done (G2 precedes G1 in program order)

        // ---------- pack: bias+relu+bf16 -> hs frag-major (verbatim r5-r9;
        // fragid = (2*wid + (m>>1))*2 + tp, kt local to this fchunk)
#pragma unroll
        for (int tp = 0; tp < 2; ++tp) {
            const f32x16& hh = tp ? h1 : h0;
#pragma unroll
            for (int m = 0; m < 4; ++m) {
                float4 bq = *(const float4*)(b1e + fc * 256 + wid * 32 + 8 * m + 4 * g);
                float v0 = fmaxf(hh[4 * m + 0] + bq.x, 0.f);
                float v1 = fmaxf(hh[4 * m + 1] + bq.y, 0.f);
                float v2 = fmaxf(hh[4 * m + 2] + bq.z, 0.f);
                float v3 = fmaxf(hh[4 * m + 3] + bq.w, 0.f);
                uint2 pk;
                pk.x = (unsigned)f2bf(v0) | ((unsigned)f2bf(v1) << 16);
                pk.y = (unsigned)f2bf(v2) | ((unsigned)f2bf(v3) << 16);
                const int fragid = (2 * wid + (m >> 1)) * 2 + tp;
                *(uint2*)&hs[fragid * 512 + ((m & 1) * 32 + l31) * 8 + 4 * g] = pk;
            }
        }

        // ---------- prefetch first w2 frag above the barrier
        const short* w2p = w2e + ((size_t)wid * 64 + fc * 16) * 512 + lane * 8;
        bf16x8 wcur = *(const bf16x8*)(w2p);

        BARRIER();   // hs ready; in-flight vmem NOT drained

        // ---------- GEMM2: wave wid -> cols [wid*32, +32), k over 256 f
        __builtin_amdgcn_s_setprio(1);
        {
            bf16x8 ha0 = *(const bf16x8*)&hs[0 * 512 + lane * 8];
            bf16x8 ha1 = *(const bf16x8*)&hs[1 * 512 + lane * 8];
#pragma unroll
            for (int kt = 0; kt < 16; ++kt) {
                bf16x8 wn, hb0, hb1;
                if (kt < 15) {
                    wn  = *(const bf16x8*)(w2p + (kt + 1) * 512);
                    hb0 = *(const bf16x8*)&hs[((kt + 1) * 2 + 0) * 512 + lane * 8];
                    hb1 = *(const bf16x8*)&hs[((kt + 1) * 2 + 1) * 512 + lane * 8];
                }
                acc[0] = __builtin_amdgcn_mfma_f32_32x32x16_bf16(ha0, wcur, acc[0], 0, 0, 0);
                acc[1] = __builtin_amdgcn_mfma_f32_32x32x16_bf16(ha1, wcur, acc[1], 0, 0, 0);
                if (kt < 15) { wcur = wn; ha0 = hb0; ha1 = hb1; }
            }
        }
        __builtin_amdgcn_s_setprio(0);
    }

    // ---- epilogue ----
    const float* b2e = b2 + e * D;
    const int col = wid * 32 + l31;
    const float bv = b2e[col];
    if (staged) {
        float* ype = yp + ((size_t)e * N_TOK + row0) * 256;
#pragma unroll
        for (int tp = 0; tp < 2; ++tp) {
#pragma unroll
            for (int r = 0; r < 16; ++r) {
                const int tl = tp * 32 + (r & 3) + 8 * (r >> 2) + 4 * g;
                if (tok_s[tl] >= 0)
                    __builtin_nontemporal_store(
                        (acc[tp][r] + bv) * p_s[tl],
                        &ype[(size_t)tl * 256 + col]);
            }
        }
    } else {
#pragma unroll
        for (int tp = 0; tp < 2; ++tp) {
#pragma unroll
            for (int r = 0; r < 16; ++r) {
                const int tl = tp * 32 + (r & 3) + 8 * (r >> 2) + 4 * g;
                const int tk = tok_s[tl];
                if (tk >= 0)
                    atomicAdd(out + (size_t)tk * D + col,
                              (acc[tp][r] + bv) * p_s[tl]);
            }
        }
    }
}

// ===========================================================================
// Combine: out[t] = yp[o1] + yp[o2]. One wave per token row.
// ===========================================================================
__global__ __launch_bounds__(256) void combine(
    const float* __restrict__ yp, const int2* __restrict__ opos,
    float* __restrict__ out) {
    const int gid   = blockIdx.x * 256 + threadIdx.x;  // float4 index
    const int t     = gid >> 6;
    const int lane4 = gid & 63;
    const int2 o = opos[t];
    const float4 a = ((const float4*)yp)[(size_t)o.x * 64 + lane4];
    const float4 b = ((const float4*)yp)[(size_t)o.y * 64 + lane4];
    float4 r;
    r.x = a.x + b.x; r.y = a.y + b.y; r.z = a.z + b.z; r.w = a.w + b.w;
    ((float4*)out)[gid] = r;
}

// ---------------------------------------------------------------------------
extern "C" void kernel_launch(void* const* d_in, const int* in_sizes, int n_in,
                              void* d_out, int out_size, void* d_ws, size_t ws_size,
                              hipStream_t stream) {
    const float* x  = (const float*)d_in[0];
    const float* gw = (const float*)d_in[1];
    const float* gb = (const float*)d_in[2];
    const float* w1 = (const float*)d_in[3];
    const float* b1 = (const float*)d_in[4];
    const float* w2 = (const float*)d_in[5];
    const float* b2 = (const float*)d_in[6];
    float* out = (float*)d_out;

    // ws: cnt 256B | bidx 1MB | bp 1MB | opos 512KB | w1f 4MB | w2f 4MB
    //   | yp 64MB (staged partials).
    char* ws = (char*)d_ws;
    size_t off = 0;
    int*   cnt   = (int*)(ws + off);  off += 256;
    int*   bidx  = (int*)(ws + off);  off += (size_t)NE * N_TOK * 4;
    float* bp    = (float*)(ws + off); off += (size_t)NE * N_TOK * 4;
    int2*  opos  = (int2*)(ws + off); off += (size_t)N_TOK * 8;
    short* w1f   = (short*)(ws + off); off += (size_t)NE * D * DFF * 2;
    short* w2f   = (short*)(ws + off); off += (size_t)NE * D * DFF * 2;
    float* yp    = (float*)(ws + off); off += (size_t)2 * N_TOK * D * 4;
    const int staged = (ws_size >= off) ? 1 : 0;

    hipMemsetAsync(cnt, 0, 256, stream);
    if (!staged)
        hipMemsetAsync(d_out, 0, (size_t)out_size * sizeof(float), stream);

    // prep first: weights land in L2 while gate runs
    wf_prep<<<2048, 256, 0, stream>>>(w1, w2, w1f, w2f);
    gate_all<<<N_TOK / 256, 256, 0, stream>>>(x, gw, gb, cnt, bidx, bp, opos);
    expert_ffn<<<NE * (N_TOK / TB), 512, 0, stream>>>(x, w1f, w2f, b1, b2,
                                                      cnt, bidx, bp, out, yp, staged);
    if (staged)
        combine<<<(N_TOK * D / 4) / 256, 256, 0, stream>>>(yp, opos, out);
}